// Round 1
// baseline (2839.954 us; speedup 1.0000x reference)
//
#include <hip/hip_runtime.h>
#include <math.h>

#define NTOK 16384
#define DIMF 1024
#define NH 16
#define DHD 64

__device__ __forceinline__ float wsum(float v) {
  v += __shfl_xor(v, 32, 64);
  v += __shfl_xor(v, 16, 64);
  v += __shfl_xor(v, 8, 64);
  v += __shfl_xor(v, 4, 64);
  v += __shfl_xor(v, 2, 64);
  v += __shfl_xor(v, 1, 64);
  return v;
}

// ---------------- GEMM: C[M,N] = A[M,K] * B[N,K]^T (+bias) ----------------
// 128x128 tile, BK=16, 256 threads, 8x(4+4) micro-tile per thread.
// LDS stored [k][m] (transposed) so inner loop reads are ds_read_b128.
__global__ __launch_bounds__(256) void gemm_nt(const float* __restrict__ A,
                                               const float* __restrict__ B,
                                               const float* __restrict__ bias,
                                               float* __restrict__ C,
                                               int M, int Nn, int K) {
  __shared__ float As[16][132];
  __shared__ float Bs[16][132];
  const int tid = threadIdx.x;
  const int m0 = blockIdx.x * 128;
  const int n0 = blockIdx.y * 128;
  const int ty = tid >> 4;       // 0..15 -> rows ty*8..+7
  const int tx = tid & 15;       // 0..15 -> cols tx*4..+3 and 64+tx*4..+3
  const int r = tid >> 2;        // 0..63 staging row
  const int kc = (tid & 3) << 2; // 0,4,8,12 staging k-col

  float acc[8][8];
  #pragma unroll
  for (int i = 0; i < 8; ++i)
    #pragma unroll
    for (int j = 0; j < 8; ++j) acc[i][j] = 0.f;

  for (int k0 = 0; k0 < K; k0 += 16) {
    #pragma unroll
    for (int half = 0; half < 2; ++half) {
      int rr = r + half * 64;
      float4 av = *(const float4*)&A[(size_t)(m0 + rr) * K + k0 + kc];
      As[kc + 0][rr] = av.x; As[kc + 1][rr] = av.y;
      As[kc + 2][rr] = av.z; As[kc + 3][rr] = av.w;
      float4 bv = *(const float4*)&B[(size_t)(n0 + rr) * K + k0 + kc];
      Bs[kc + 0][rr] = bv.x; Bs[kc + 1][rr] = bv.y;
      Bs[kc + 2][rr] = bv.z; Bs[kc + 3][rr] = bv.w;
    }
    __syncthreads();
    #pragma unroll
    for (int kk = 0; kk < 16; ++kk) {
      float4 a0 = *(const float4*)&As[kk][ty * 8];
      float4 a1 = *(const float4*)&As[kk][ty * 8 + 4];
      float4 b0 = *(const float4*)&Bs[kk][tx * 4];
      float4 b1 = *(const float4*)&Bs[kk][tx * 4 + 64];
      float a[8] = {a0.x, a0.y, a0.z, a0.w, a1.x, a1.y, a1.z, a1.w};
      float b[8] = {b0.x, b0.y, b0.z, b0.w, b1.x, b1.y, b1.z, b1.w};
      #pragma unroll
      for (int i = 0; i < 8; ++i)
        #pragma unroll
        for (int j = 0; j < 8; ++j) acc[i][j] = fmaf(a[i], b[j], acc[i][j]);
    }
    __syncthreads();
  }
  #pragma unroll
  for (int i = 0; i < 8; ++i) {
    int row = m0 + ty * 8 + i;
    int c0 = n0 + tx * 4;
    int c1 = n0 + 64 + tx * 4;
    float4 o0 = make_float4(acc[i][0], acc[i][1], acc[i][2], acc[i][3]);
    float4 o1 = make_float4(acc[i][4], acc[i][5], acc[i][6], acc[i][7]);
    if (bias) {
      o0.x += bias[c0]; o0.y += bias[c0 + 1]; o0.z += bias[c0 + 2]; o0.w += bias[c0 + 3];
      o1.x += bias[c1]; o1.y += bias[c1 + 1]; o1.z += bias[c1 + 2]; o1.w += bias[c1 + 3];
    }
    *(float4*)&C[(size_t)row * Nn + c0] = o0;
    *(float4*)&C[(size_t)row * Nn + c1] = o1;
  }
}

// ---------------- logmap0 per (token,head): wave = one token row ----------
__global__ __launch_bounds__(256) void logmap_kernel(const float* __restrict__ in,
                                                     float* __restrict__ out,
                                                     const float* __restrict__ c) {
  int lane = threadIdx.x & 63;
  int wid = blockIdx.x * 4 + (threadIdx.x >> 6);
  int nw = gridDim.x * 4;
  for (int rrow = wid; rrow < NTOK; rrow += nw) {
    #pragma unroll
    for (int h = 0; h < NH; ++h) {
      int idx = rrow * DIMF + h * DHD + lane;
      float y = in[idx];
      float s = wsum(y * y);
      float yn = fmaxf(sqrtf(s), 1e-15f);
      float k = c[h];
      float sk = sqrtf(fmaxf(fabsf(k), 1e-15f));
      float t = fminf(yn * sk, 1.f - 1e-7f);
      float ar = atanhf(t) / sk;
      out[idx] = (ar / yn) * y;
    }
  }
}

// ------- stereo epilogue: expmap0 -> project -> mobius_add(bias) -> project
__global__ __launch_bounds__(256) void stereo_epi_kernel(const float* __restrict__ in,
                                                         float* __restrict__ out,
                                                         const float* __restrict__ bvec,
                                                         const float* __restrict__ c) {
  int lane = threadIdx.x & 63;
  int wid = blockIdx.x * 4 + (threadIdx.x >> 6);
  int nw = gridDim.x * 4;
  for (int rrow = wid; rrow < NTOK; rrow += nw) {
    #pragma unroll
    for (int h = 0; h < NH; ++h) {
      int idx = rrow * DIMF + h * DHD + lane;
      float k = c[h];
      float ak = fmaxf(fabsf(k), 1e-15f);
      float sk = sqrtf(ak);
      float maxn = (1.f - 1e-5f) / sk;
      float v = in[idx];
      float s = wsum(v * v);
      float un = fmaxf(sqrtf(s), 1e-15f);
      float tn = tanhf(un * sk) / sk;
      v *= tn / un;
      float rn = fmaxf(tn, 1e-15f);
      if (rn > maxn) { v *= maxn / rn; rn = maxn; }
      float b = bvec[h * DHD + lane];
      float bs = wsum(b * b);
      float bn = fmaxf(sqrtf(bs), 1e-15f);
      float tb = tanhf(bn * sk) / sk;
      float sb = (tb / bn) * b;
      float sbn = fmaxf(tb, 1e-15f);
      if (sbn > maxn) { sb *= maxn / sbn; sbn = maxn; }
      float x2 = rn * rn, y2 = sbn * sbn;
      float xy = wsum(v * sb);
      float num1 = 1.f - 2.f * k * xy - k * y2;
      float num2 = 1.f + k * x2;
      float numx = num1 * v + num2 * sb;
      float den = fmaxf(1.f - 2.f * k * xy + k * k * x2 * y2, 1e-15f);
      float o = numx / den;
      float os = wsum(o * o);
      float on = fmaxf(sqrtf(os), 1e-15f);
      if (on > maxn) o *= maxn / on;
      out[idx] = o;
    }
  }
}

// ------- attention pass 1: Q->v1, K->v2, V->x (in place) + v2_sum ---------
__global__ __launch_bounds__(256) void attn_pass1(float* __restrict__ Q,
                                                  float* __restrict__ Kb,
                                                  float* __restrict__ V,
                                                  const float* __restrict__ mask,
                                                  const float* __restrict__ c,
                                                  float* __restrict__ v2sum) {
  __shared__ float bacc[1024];
  int tid = threadIdx.x;
  for (int i = tid; i < 1024; i += 256) bacc[i] = 0.f;
  __syncthreads();
  int lane = tid & 63;
  int wid = blockIdx.x * 4 + (tid >> 6);
  int nw = gridDim.x * 4;
  float acc[NH];
  #pragma unroll
  for (int h = 0; h < NH; ++h) acc[h] = 0.f;
  for (int rrow = wid; rrow < NTOK; rrow += nw) {
    float m = mask[rrow];
    #pragma unroll
    for (int h = 0; h < NH; ++h) {
      int idx = rrow * DIMF + h * DHD + lane;
      float k = c[h];
      float vv = V[idx];
      float sv = wsum(vv * vv);
      float pt = fmaxf(1.f + k * sv, 1e-15f);
      float gamma = fmaxf(2.f / pt, 1e-15f);
      float gm1 = gamma - 1.f;
      float aden = fmaxf(fabsf(gm1), 1e-10f);
      float den = (gm1 >= 0.f) ? aden : -aden;
      float q = Q[idx] / pt;
      float v1 = ((q > 0.f) ? q : expm1f(q)) + 1.f;
      Q[idx] = v1;
      float kv = Kb[idx] / pt;
      float v2 = den * (((kv > 0.f) ? kv : expm1f(kv)) + 1.f) * m;
      Kb[idx] = v2;
      acc[h] += v2;
      V[idx] = (gamma / den) * vv * m;
    }
  }
  #pragma unroll
  for (int h = 0; h < NH; ++h) atomicAdd(&bacc[h * DHD + lane], acc[h]);
  __syncthreads();
  for (int i = tid; i < 1024; i += 256) atomicAdd(&v2sum[i], bacc[i]);
}

// ------- attention pass 2: ctx[h,d,e] = sum_n v2[n,h,d]*x[n,h,e] ----------
#define TOK2 256
__global__ __launch_bounds__(256) void attn_pass2(const float* __restrict__ v2,
                                                  const float* __restrict__ x,
                                                  float* __restrict__ ctx) {
  __shared__ float v2s[8][64];
  __shared__ float xs[8][64];
  int tid = threadIdx.x;
  int h = blockIdx.y;
  int n0 = blockIdx.x * TOK2;
  int e = tid & 63;
  int dg = tid >> 6; // 0..3
  float acc[16];
  #pragma unroll
  for (int i = 0; i < 16; ++i) acc[i] = 0.f;
  for (int t = 0; t < TOK2; t += 8) {
    __syncthreads();
    #pragma unroll
    for (int j = 0; j < 2; ++j) {
      int li = tid + j * 256;
      int tt = li >> 6;
      int l = li & 63;
      size_t gidx = (size_t)(n0 + t + tt) * DIMF + h * DHD + l;
      v2s[tt][l] = v2[gidx];
      xs[tt][l] = x[gidx];
    }
    __syncthreads();
    #pragma unroll
    for (int tt = 0; tt < 8; ++tt) {
      float xv = xs[tt][e];
      #pragma unroll
      for (int i = 0; i < 16; ++i) acc[i] = fmaf(v2s[tt][dg * 16 + i], xv, acc[i]);
    }
  }
  #pragma unroll
  for (int i = 0; i < 16; ++i)
    atomicAdd(&ctx[h * 4096 + (dg * 16 + i) * 64 + e], acc[i]);
}

// ------- attention pass 3: Xo = D_inv * v1 @ ctx, then mobius epilogue ----
__global__ __launch_bounds__(256) void attn_pass3(const float* __restrict__ v1buf,
                                                  const float* __restrict__ ctx,
                                                  const float* __restrict__ v2sum,
                                                  const float* __restrict__ c,
                                                  float* __restrict__ A) {
  __shared__ float ctxs[64][64];
  int tid = threadIdx.x;
  int h = blockIdx.y;
  {
    const float4* src = (const float4*)&ctx[h * 4096];
    float4* dst = (float4*)&ctxs[0][0];
    for (int i = tid; i < 1024; i += 256) dst[i] = src[i];
  }
  int lane = tid & 63;
  int w = tid >> 6;
  float vs = v2sum[h * DHD + lane];
  float k = c[h];
  float ak = fmaxf(fabsf(k), 1e-15f);
  float sk = sqrtf(ak);
  float maxn = (1.f - 1e-5f) / sk;
  __syncthreads();
  int r0 = blockIdx.x * 32 + w * 8;
  for (int rr = r0; rr < r0 + 8; ++rr) {
    int idx = rr * DIMF + h * DHD + lane;
    float v1 = v1buf[idx];
    float Dn = wsum(v1 * vs);
    float D = (Dn == 0.f) ? 1e-5f : Dn;
    float Dinv = 1.f / D;
    float xo = 0.f;
    #pragma unroll
    for (int d = 0; d < 64; ++d)
      xo = fmaf(__shfl(v1, d, 64), ctxs[d][lane], xo);
    xo *= Dinv;
    float n2 = wsum(xo * xo);
    float xn = fmaxf(sqrtf(n2), 1e-15f);
    if (xn > maxn) { xo *= maxn / xn; xn = maxn; }
    float t = fminf(xn * sk, 1.f - 1e-7f);
    float ar = atanhf(t) / sk;
    float tk = tanhf(0.5f * ar * sk) / sk;
    xo *= tk / xn;
    float nn = fmaxf(fabsf(tk), 1e-15f);
    if (nn > maxn) xo *= maxn / nn;
    A[idx] = xo;
  }
}

extern "C" void kernel_launch(void* const* d_in, const int* in_sizes, int n_in,
                              void* d_out, int out_size, void* d_ws, size_t ws_size,
                              hipStream_t stream) {
  const float* X    = (const float*)d_in[0];
  const float* mask = (const float*)d_in[1];
  const float* Wq   = (const float*)d_in[2];
  const float* bq   = (const float*)d_in[3];
  const float* Wk   = (const float*)d_in[4];
  const float* bk   = (const float*)d_in[5];
  const float* Wv   = (const float*)d_in[6];
  const float* bv   = (const float*)d_in[7];
  const float* c_v  = (const float*)d_in[8];
  const float* c_at = (const float*)d_in[9];
  const float* Wff  = (const float*)d_in[10];
  const float* bff  = (const float*)d_in[11];
  const float* c_ff = (const float*)d_in[12];
  float* out = (float*)d_out;

  float* buf1 = (float*)d_ws;                        // 64 MB
  float* buf2 = buf1 + (size_t)NTOK * DIMF;          // 64 MB
  float* buf3 = buf2 + (size_t)NTOK * DIMF;          // 64 MB
  float* v2sum = buf3 + (size_t)NTOK * DIMF;         // 4 KB
  float* ctx = v2sum + 1024;                         // 256 KB

  dim3 gg(NTOK / 128, DIMF / 128);

  // V = stereo_linear(X, Wv, bv, c_v)
  logmap_kernel<<<512, 256, 0, stream>>>(X, buf1, c_v);
  gemm_nt<<<gg, 256, 0, stream>>>(buf1, Wv, nullptr, buf2, NTOK, DIMF, DIMF);
  stereo_epi_kernel<<<512, 256, 0, stream>>>(buf2, buf2, bv, c_v);
  // Q, K
  gemm_nt<<<gg, 256, 0, stream>>>(X, Wq, bq, buf1, NTOK, DIMF, DIMF);
  gemm_nt<<<gg, 256, 0, stream>>>(X, Wk, bk, buf3, NTOK, DIMF, DIMF);
  // attention
  hipMemsetAsync(v2sum, 0, (1024 + 65536) * sizeof(float), stream);
  attn_pass1<<<256, 256, 0, stream>>>(buf1, buf3, buf2, mask, c_at, v2sum);
  attn_pass2<<<dim3(NTOK / TOK2, NH), 256, 0, stream>>>(buf3, buf2, ctx);
  attn_pass3<<<dim3(NTOK / 32, NH), 256, 0, stream>>>(buf1, ctx, v2sum, c_at, buf2);
  // out = stereo_linear(A, Wff, bff, c_ff)
  logmap_kernel<<<512, 256, 0, stream>>>(buf2, buf1, c_ff);
  gemm_nt<<<gg, 256, 0, stream>>>(buf1, Wff, nullptr, buf3, NTOK, DIMF, DIMF);
  stereo_epi_kernel<<<512, 256, 0, stream>>>(buf3, out, bff, c_ff);
}

// Round 2
// 1315.461 us; speedup vs baseline: 2.1589x; 2.1589x over previous
//
#include <hip/hip_runtime.h>
#include <math.h>
#include <stdint.h>

#define NTOK 16384
#define DIMF 1024
#define NH 16
#define DHD 64

typedef _Float16 half_t;
typedef __attribute__((ext_vector_type(8))) _Float16 half8;
typedef __attribute__((ext_vector_type(4))) _Float16 half4;
typedef __attribute__((ext_vector_type(4))) float floatx4;

__device__ __forceinline__ float wsum(float v) {
  v += __shfl_xor(v, 32, 64);
  v += __shfl_xor(v, 16, 64);
  v += __shfl_xor(v, 8, 64);
  v += __shfl_xor(v, 4, 64);
  v += __shfl_xor(v, 2, 64);
  v += __shfl_xor(v, 1, 64);
  return v;
}
__device__ __forceinline__ float wsum16(float v) {
  v += __shfl_xor(v, 1, 64);
  v += __shfl_xor(v, 2, 64);
  v += __shfl_xor(v, 4, 64);
  v += __shfl_xor(v, 8, 64);
  return v;
}

__device__ __forceinline__ float frcp(float x) { return __builtin_amdgcn_rcpf(x); }
__device__ __forceinline__ float fexp(float x) { return __expf(x); }
__device__ __forceinline__ float flog(float x) { return __logf(x); }
// tanh for x >= 0
__device__ __forceinline__ float ftanh_pos(float x) {
  float e = fexp(2.f * x);
  return 1.f - 2.f * frcp(e + 1.f);
}
// atanh for t in [0, 1)
__device__ __forceinline__ float fatanh01(float t) {
  return 0.5f * flog((1.f + t) * frcp(1.f - t));
}

__device__ __forceinline__ void gload16(const void* g, void* lds) {
  __builtin_amdgcn_global_load_lds(
      (const __attribute__((address_space(1))) uint32_t*)(uintptr_t)g,
      (__attribute__((address_space(3))) uint32_t*)(uintptr_t)lds, 16, 0, 0);
}

// =============== GEMM: C[M,N] = A[M,K](f16) * (Bh+Bl)[N,K]^T (+bias) ======
// 128x128 tile, BK=64, 256 thr, per-wave 4x4 grid of 16x16x32 f16 MFMAs,
// 2 MFMAs per tile (B hi + B lo) into the same accumulator.
// LDS is "fragment-canonical": 1KB blocks of 64 chunks x 16B, chunk index ==
// reading lane, so ds_read_b128 is conflict-free and global_load_lds legal.
template <typename OutT>
__global__ __launch_bounds__(256, 3) void gemm_f16(const half_t* __restrict__ A,
                                                   const half_t* __restrict__ Bh,
                                                   const half_t* __restrict__ Bl,
                                                   const float* __restrict__ bias,
                                                   OutT* __restrict__ C,
                                                   int M, int Nn, int K) {
  __shared__ half_t sA[128 * 64];
  __shared__ half_t sBh[128 * 64];
  __shared__ half_t sBl[128 * 64];
  const int tid = threadIdx.x;
  const int lane = tid & 63;
  const int w = tid >> 6;
  const int n0 = blockIdx.x * 128;
  const int m0 = blockIdx.y * 128;

  const half_t* srcA[4];
  const half_t* srcBh[4];
  const half_t* srcBl[4];
  int dstOff[4];
#pragma unroll
  for (int t = 0; t < 4; ++t) {
    int idx = w * 4 + t;
    int ks = idx >> 3, g = idx & 7;
    int row = g * 16 + (lane & 15);
    int kof = ks * 32 + (lane >> 4) * 8;
    srcA[t] = A + (size_t)(m0 + row) * K + kof;
    srcBh[t] = Bh + (size_t)(n0 + row) * K + kof;
    srcBl[t] = Bl + (size_t)(n0 + row) * K + kof;
    dstOff[t] = (ks * 8 + g) * 512;  // in f16 elements (1KB blocks)
  }

  floatx4 acc[4][4];
#pragma unroll
  for (int i = 0; i < 4; ++i)
#pragma unroll
    for (int j = 0; j < 4; ++j) acc[i][j] = (floatx4){0.f, 0.f, 0.f, 0.f};

  const int wr = (w >> 1) * 4;  // row-group base (of 8)
  const int wc = (w & 1) * 4;   // col-group base (of 8)

  for (int k0 = 0; k0 < K; k0 += 64) {
#pragma unroll
    for (int t = 0; t < 4; ++t) {
      gload16(srcA[t], sA + dstOff[t]);
      gload16(srcBh[t], sBh + dstOff[t]);
      gload16(srcBl[t], sBl + dstOff[t]);
      srcA[t] += 64;
      srcBh[t] += 64;
      srcBl[t] += 64;
    }
    __syncthreads();  // compiler drains vmcnt before s_barrier -> staging done
#pragma unroll
    for (int ks = 0; ks < 2; ++ks) {
      half8 af[4], bhf[4], blf[4];
#pragma unroll
      for (int i = 0; i < 4; ++i)
        af[i] = *(const half8*)&sA[(ks * 8 + wr + i) * 512 + lane * 8];
#pragma unroll
      for (int j = 0; j < 4; ++j) {
        bhf[j] = *(const half8*)&sBh[(ks * 8 + wc + j) * 512 + lane * 8];
        blf[j] = *(const half8*)&sBl[(ks * 8 + wc + j) * 512 + lane * 8];
      }
#pragma unroll
      for (int i = 0; i < 4; ++i)
#pragma unroll
        for (int j = 0; j < 4; ++j) {
          acc[i][j] = __builtin_amdgcn_mfma_f32_16x16x32_f16(af[i], bhf[j], acc[i][j], 0, 0, 0);
          acc[i][j] = __builtin_amdgcn_mfma_f32_16x16x32_f16(af[i], blf[j], acc[i][j], 0, 0, 0);
        }
    }
    __syncthreads();  // readers done before next stage overwrites
  }
  // epilogue: C row = quad*4+reg, col = lane&15 within each 16x16 tile
  const int e = lane & 15;
  const int quad = lane >> 4;
#pragma unroll
  for (int j = 0; j < 4; ++j) {
    int col = n0 + (w & 1) * 64 + j * 16 + e;
    float bv = bias ? bias[col] : 0.f;
#pragma unroll
    for (int i = 0; i < 4; ++i) {
      int row = m0 + (w >> 1) * 64 + i * 16 + quad * 4;
#pragma unroll
      for (int r = 0; r < 4; ++r)
        C[(size_t)(row + r) * Nn + col] = (OutT)(acc[i][j][r] + bv);
    }
  }
}

// =============== weight split fp32 -> f16 hi + f16 lo =====================
struct WPack {
  const float* w[4];
  half_t* h[4];
  half_t* l[4];
};
__global__ __launch_bounds__(256) void convert_w_kernel(WPack pk) {
  int wi = blockIdx.y;
  const float* w = pk.w[wi];
  half_t* ph = pk.h[wi];
  half_t* pl = pk.l[wi];
  int i = (blockIdx.x * 256 + threadIdx.x) * 4;
  float4 v = *(const float4*)&w[i];
  half4 hh, ll;
  hh.x = (half_t)v.x; ll.x = (half_t)(v.x - (float)hh.x);
  hh.y = (half_t)v.y; ll.y = (half_t)(v.y - (float)hh.y);
  hh.z = (half_t)v.z; ll.z = (half_t)(v.z - (float)hh.z);
  hh.w = (half_t)v.w; ll.w = (half_t)(v.w - (float)hh.w);
  *(half4*)&ph[i] = hh;
  *(half4*)&pl[i] = ll;
}

// =============== prep: Xh = f16(X); U = f16(logmap0(X, c_v)) ==============
__global__ __launch_bounds__(256) void prep_kernel(const float* __restrict__ X,
                                                   half_t* __restrict__ Xh,
                                                   half_t* __restrict__ U,
                                                   const float* __restrict__ c) {
  int lane = threadIdx.x & 63;
  int wid = blockIdx.x * 4 + (threadIdx.x >> 6);
  int nw = gridDim.x * 4;
  for (int row = wid; row < NTOK; row += nw) {
#pragma unroll
    for (int h = 0; h < NH; ++h) {
      int idx = row * DIMF + h * DHD + lane;
      float x = X[idx];
      Xh[idx] = (half_t)x;
      float s = wsum(x * x);
      float yn = fmaxf(sqrtf(s), 1e-15f);
      float k = c[h];
      float sk = sqrtf(fmaxf(fabsf(k), 1e-15f));
      float t = fminf(yn * sk, 1.f - 1e-7f);
      float ar = fatanh01(t) * frcp(sk);
      U[idx] = (half_t)(ar * frcp(yn) * x);
    }
  }
}

// ======= stereo epilogue: expmap0 -> project -> mobius_add(b) -> project ==
__global__ __launch_bounds__(256) void stereo_epi(const float* __restrict__ in,
                                                  float* __restrict__ out,
                                                  const float* __restrict__ bvec,
                                                  const float* __restrict__ c) {
  int lane = threadIdx.x & 63;
  int wid = blockIdx.x * 4 + (threadIdx.x >> 6);
  int nw = gridDim.x * 4;
  for (int row = wid; row < NTOK; row += nw) {
#pragma unroll
    for (int h = 0; h < NH; ++h) {
      int idx = row * DIMF + h * DHD + lane;
      float k = c[h];
      float ak = fmaxf(fabsf(k), 1e-15f);
      float sk = sqrtf(ak);
      float rsk = frcp(sk);
      float maxn = (1.f - 1e-5f) * rsk;
      float v = in[idx];
      float s = wsum(v * v);
      float un = fmaxf(sqrtf(s), 1e-15f);
      float tn = ftanh_pos(un * sk) * rsk;
      v *= tn * frcp(un);
      float rn = fmaxf(tn, 1e-15f);
      if (rn > maxn) { v *= maxn * frcp(rn); rn = maxn; }
      float b = bvec[h * DHD + lane];
      float bs = wsum(b * b);
      float bn = fmaxf(sqrtf(bs), 1e-15f);
      float tb = ftanh_pos(bn * sk) * rsk;
      float sb = tb * frcp(bn) * b;
      float sbn = fmaxf(tb, 1e-15f);
      if (sbn > maxn) { sb *= maxn * frcp(sbn); sbn = maxn; }
      float x2 = rn * rn, y2 = sbn * sbn;
      float xy = wsum(v * sb);
      float num1 = 1.f - 2.f * k * xy - k * y2;
      float num2 = 1.f + k * x2;
      float numx = num1 * v + num2 * sb;
      float den = fmaxf(1.f - 2.f * k * xy + k * k * x2 * y2, 1e-15f);
      float o = numx * frcp(den);
      float os = wsum(o * o);
      float on = fmaxf(sqrtf(os), 1e-15f);
      if (on > maxn) o *= maxn * frcp(on);
      out[idx] = o;
    }
  }
}

// ======= attention pass 1: Qh->v1h, Kh->v2h (in place), V(f32)->xh ========
__global__ __launch_bounds__(256) void attn_pass1(half_t* __restrict__ Qh,
                                                  half_t* __restrict__ Kh,
                                                  const float* __restrict__ V,
                                                  half_t* __restrict__ xh,
                                                  const float* __restrict__ mask,
                                                  const float* __restrict__ c,
                                                  float* __restrict__ v2sum) {
  __shared__ float bacc[1024];
  int tid = threadIdx.x;
  for (int i = tid; i < 1024; i += 256) bacc[i] = 0.f;
  __syncthreads();
  int lane = tid & 63;
  int wid = blockIdx.x * 4 + (tid >> 6);
  int nw = gridDim.x * 4;
  float acc[NH];
#pragma unroll
  for (int h = 0; h < NH; ++h) acc[h] = 0.f;
  for (int row = wid; row < NTOK; row += nw) {
    float m = mask[row];
#pragma unroll
    for (int h = 0; h < NH; ++h) {
      int idx = row * DIMF + h * DHD + lane;
      float k = c[h];
      float vv = V[idx];
      float sv = wsum(vv * vv);
      float pt = fmaxf(1.f + k * sv, 1e-15f);
      float rpt = frcp(pt);
      float gamma = fmaxf(2.f * rpt, 1e-15f);
      float gm1 = gamma - 1.f;
      float aden = fmaxf(fabsf(gm1), 1e-10f);
      float den = (gm1 >= 0.f) ? aden : -aden;
      float q = (float)Qh[idx] * rpt;
      float v1 = (q > 0.f) ? (q + 1.f) : fexp(q);  // elu+1 == e^x for x<=0
      Qh[idx] = (half_t)v1;
      float kv = (float)Kh[idx] * rpt;
      float v2 = den * ((kv > 0.f) ? (kv + 1.f) : fexp(kv)) * m;
      Kh[idx] = (half_t)v2;
      acc[h] += v2;
      xh[idx] = (half_t)(gamma * frcp(den) * vv * m);
    }
  }
#pragma unroll
  for (int h = 0; h < NH; ++h) atomicAdd(&bacc[h * DHD + lane], acc[h]);
  __syncthreads();
  for (int i = tid; i < 1024; i += 256) atomicAdd(&v2sum[i], bacc[i]);
}

// ======= pass D: Dinv[n,h] = 1/dot(v1h[n,h,:], v2sum[h,:]) ================
__global__ __launch_bounds__(256) void passD_kernel(const half_t* __restrict__ v1h,
                                                    const float* __restrict__ v2sum,
                                                    float* __restrict__ Dinv) {
  int lane = threadIdx.x & 63;
  int wid = blockIdx.x * 4 + (threadIdx.x >> 6);
  int nw = gridDim.x * 4;
  for (int row = wid; row < NTOK; row += nw) {
#pragma unroll
    for (int h = 0; h < NH; ++h) {
      float v = (float)v1h[row * DIMF + h * DHD + lane];
      float s = wsum(v * v2sum[h * DHD + lane]);
      if (lane == 0) {
        float D = (s == 0.f) ? 1e-5f : s;
        Dinv[(size_t)row * NH + h] = 1.f / D;
      }
    }
  }
}

// ======= pass 2: ctxT[h][e][d] = sum_n v2h[n,h,d]*xh[n,h,e] ===============
#define TOK2 1024
__global__ __launch_bounds__(256) void attn_pass2(const half_t* __restrict__ v2h,
                                                  const half_t* __restrict__ xh,
                                                  float* __restrict__ ctxT) {
  __shared__ float v2s[8][64];
  __shared__ float xs[8][64];
  int tid = threadIdx.x;
  int h = blockIdx.y;
  int n0 = blockIdx.x * TOK2;
  int e = tid & 63;
  int dg = tid >> 6;  // 0..3 (uniform per wave)
  float acc[16];
#pragma unroll
  for (int i = 0; i < 16; ++i) acc[i] = 0.f;
  for (int t = 0; t < TOK2; t += 8) {
    __syncthreads();
#pragma unroll
    for (int j = 0; j < 2; ++j) {
      int li = tid + j * 256;
      int tt = li >> 6;
      int l = li & 63;
      size_t g = (size_t)(n0 + t + tt) * DIMF + h * DHD + l;
      v2s[tt][l] = (float)v2h[g];
      xs[tt][l] = (float)xh[g];
    }
    __syncthreads();
#pragma unroll
    for (int tt = 0; tt < 8; ++tt) {
      float xv = xs[tt][e];
#pragma unroll
      for (int i = 0; i < 16; ++i) acc[i] = fmaf(v2s[tt][dg * 16 + i], xv, acc[i]);
    }
  }
#pragma unroll
  for (int i = 0; i < 16; ++i)
    atomicAdd(&ctxT[h * 4096 + e * 64 + dg * 16 + i], acc[i]);
}

// ======= pass 3 (MFMA): Xo = Dinv * (v1h @ ctx), fused mobius epi + logmap
// Block: 64 rows x 1 head. Wave w handles rows m0+w*16..+15 via 16x16x32
// MFMAs against ctxT staged in LDS (fragment-canonical, f16).
__global__ __launch_bounds__(256) void attn_pass3m(const half_t* __restrict__ v1h,
                                                   const float* __restrict__ ctxT,
                                                   const float* __restrict__ Dinv,
                                                   const float* __restrict__ c_at,
                                                   const float* __restrict__ c_ff,
                                                   half_t* __restrict__ Uff) {
  __shared__ half_t sctx[8 * 64 * 8];  // 8 tiles (4 n x 2 k) x 64 chunks x 8 f16
  int tid = threadIdx.x;
  int h = blockIdx.y;
  int m0 = blockIdx.x * 64;
  // stage ctxT -> LDS as f16, fragment-canonical: tile t=(ks*4+j), chunk l:
  // e = j*16 + (l&15), d = ks*32 + (l>>4)*8
  for (int ci = tid; ci < 512; ci += 256) {
    int t = ci >> 6, l = ci & 63;
    int j = t & 3, ks = t >> 2;
    int e = j * 16 + (l & 15);
    int d = ks * 32 + (l >> 4) * 8;
    const float* src = &ctxT[h * 4096 + e * 64 + d];
    half8 hh;
#pragma unroll
    for (int q = 0; q < 8; ++q) hh[q] = (half_t)src[q];
    *(half8*)&sctx[ci * 8] = hh;
  }
  __syncthreads();

  int lane = tid & 63;
  int w = tid >> 6;
  int quad = lane >> 4;
  int e = lane & 15;

  const half_t* ap = v1h + (size_t)(m0 + w * 16 + e) * DIMF + h * DHD + quad * 8;
  half8 a0 = *(const half8*)ap;
  half8 a1 = *(const half8*)(ap + 32);

  floatx4 acc[4];
#pragma unroll
  for (int j = 0; j < 4; ++j) acc[j] = (floatx4){0.f, 0.f, 0.f, 0.f};
#pragma unroll
  for (int j = 0; j < 4; ++j) {
    half8 b0 = *(const half8*)&sctx[((0 * 4 + j) * 64 + lane) * 8];
    half8 b1 = *(const half8*)&sctx[((1 * 4 + j) * 64 + lane) * 8];
    acc[j] = __builtin_amdgcn_mfma_f32_16x16x32_f16(a0, b0, acc[j], 0, 0, 0);
    acc[j] = __builtin_amdgcn_mfma_f32_16x16x32_f16(a1, b1, acc[j], 0, 0, 0);
  }

  float ka = c_at[h];
  float sk_a = sqrtf(fmaxf(fabsf(ka), 1e-15f));
  float rsk_a = frcp(sk_a);
  float maxn_a = (1.f - 1e-5f) * rsk_a;
  float kf = c_ff[h];
  float sk_f = sqrtf(fmaxf(fabsf(kf), 1e-15f));
  float rsk_f = frcp(sk_f);

#pragma unroll
  for (int r = 0; r < 4; ++r) {
    float v0 = acc[0][r], v1 = acc[1][r], v2 = acc[2][r], v3 = acc[3][r];
    float s = v0 * v0 + v1 * v1 + v2 * v2 + v3 * v3;
    s = wsum16(s);  // full row norm^2 (raw, pre-Dinv)
    int row = m0 + w * 16 + quad * 4 + r;
    float Di = Dinv[(size_t)row * NH + h];  // > 0
    float f = Di;
    float xn = fmaxf(sqrtf(s) * Di, 1e-15f);
    if (xn > maxn_a) { f *= maxn_a * frcp(xn); xn = maxn_a; }
    float t = fminf(xn * sk_a, 1.f - 1e-7f);
    float ar = fatanh01(t) * rsk_a;
    float tk = ftanh_pos(0.5f * ar * sk_a) * rsk_a;
    f *= tk * frcp(xn);
    float nn = tk;
    if (nn > maxn_a) { f *= maxn_a * frcp(nn); nn = maxn_a; }
    float fn = fmaxf(nn, 1e-15f);
    float t2 = fminf(fn * sk_f, 1.f - 1e-7f);
    float ar2 = fatanh01(t2) * rsk_f;
    f *= ar2 * frcp(fn);
    size_t base = (size_t)row * DIMF + h * DHD + e;
    Uff[base + 0] = (half_t)(v0 * f);
    Uff[base + 16] = (half_t)(v1 * f);
    Uff[base + 32] = (half_t)(v2 * f);
    Uff[base + 48] = (half_t)(v3 * f);
  }
}

extern "C" void kernel_launch(void* const* d_in, const int* in_sizes, int n_in,
                              void* d_out, int out_size, void* d_ws, size_t ws_size,
                              hipStream_t stream) {
  const float* X = (const float*)d_in[0];
  const float* mask = (const float*)d_in[1];
  const float* Wq = (const float*)d_in[2];
  const float* bq = (const float*)d_in[3];
  const float* Wk = (const float*)d_in[4];
  const float* bk = (const float*)d_in[5];
  const float* Wv = (const float*)d_in[6];
  const float* bv = (const float*)d_in[7];
  const float* c_v = (const float*)d_in[8];
  const float* c_at = (const float*)d_in[9];
  const float* Wff = (const float*)d_in[10];
  const float* bff = (const float*)d_in[11];
  const float* c_ff = (const float*)d_in[12];
  float* out = (float*)d_out;

  const size_t NE = (size_t)NTOK * DIMF;
  float* buf1 = (float*)d_ws;            // 64 MB fp32
  float* v2sum = buf1 + NE;              // 4 KB
  float* ctxT = v2sum + 1024;            // 256 KB
  float* Dinv = ctxT + 65536;            // 1 MB
  half_t* H1 = (half_t*)(Dinv + (size_t)NTOK * NH);  // 32 MB: Xh -> xh -> Uff
  half_t* H2 = H1 + NE;                  // 32 MB: Uv -> Qh/v1h
  half_t* H3 = H2 + NE;                  // 32 MB: Kh/v2h
  half_t* Wh0 = H3 + NE;                 // 4 x 2 MB hi
  half_t* Wl0 = Wh0 + 4 * (size_t)DIMF * DIMF;  // 4 x 2 MB lo

  WPack pk;
  pk.w[0] = Wq; pk.w[1] = Wk; pk.w[2] = Wv; pk.w[3] = Wff;
  for (int i = 0; i < 4; ++i) {
    pk.h[i] = Wh0 + (size_t)i * DIMF * DIMF;
    pk.l[i] = Wl0 + (size_t)i * DIMF * DIMF;
  }

  dim3 gg(DIMF / 128, NTOK / 128);

  convert_w_kernel<<<dim3(1024, 4), 256, 0, stream>>>(pk);
  prep_kernel<<<1024, 256, 0, stream>>>(X, H1, H2, c_v);
  // V = stereo_linear(X, Wv, bv, c_v)
  gemm_f16<float><<<gg, 256, 0, stream>>>(H2, pk.h[2], pk.l[2], nullptr, buf1, NTOK, DIMF, DIMF);
  stereo_epi<<<1024, 256, 0, stream>>>(buf1, buf1, bv, c_v);
  // Q, K (f16 outputs)
  gemm_f16<half_t><<<gg, 256, 0, stream>>>(H1, pk.h[0], pk.l[0], bq, H2, NTOK, DIMF, DIMF);
  gemm_f16<half_t><<<gg, 256, 0, stream>>>(H1, pk.h[1], pk.l[1], bk, H3, NTOK, DIMF, DIMF);
  // attention
  hipMemsetAsync(v2sum, 0, (1024 + 65536) * sizeof(float), stream);
  attn_pass1<<<512, 256, 0, stream>>>(H2, H3, buf1, H1, mask, c_at, v2sum);
  passD_kernel<<<1024, 256, 0, stream>>>(H2, v2sum, Dinv);
  attn_pass2<<<dim3(NTOK / TOK2, NH), 256, 0, stream>>>(H3, H1, ctxT);
  attn_pass3m<<<dim3(NTOK / 64, NH), 256, 0, stream>>>(H2, ctxT, Dinv, c_at, c_ff, H1);
  // out = stereo_linear(A, Wff, bff, c_ff)
  gemm_f16<float><<<gg, 256, 0, stream>>>(H1, pk.h[3], pk.l[3], nullptr, buf1, NTOK, DIMF, DIMF);
  stereo_epi<<<1024, 256, 0, stream>>>(buf1, out, bff, c_ff);
}

// Round 3
// 848.315 us; speedup vs baseline: 3.3478x; 1.5507x over previous
//
#include <hip/hip_runtime.h>
#include <math.h>
#include <stdint.h>

#define NTOK 16384
#define DIMF 1024
#define NH 16
#define DHD 64

typedef _Float16 half_t;
typedef __attribute__((ext_vector_type(8))) _Float16 half8;
typedef __attribute__((ext_vector_type(4))) _Float16 half4;
typedef __attribute__((ext_vector_type(4))) float floatx4;

__device__ __forceinline__ float wsum(float v) {
  v += __shfl_xor(v, 32, 64);
  v += __shfl_xor(v, 16, 64);
  v += __shfl_xor(v, 8, 64);
  v += __shfl_xor(v, 4, 64);
  v += __shfl_xor(v, 2, 64);
  v += __shfl_xor(v, 1, 64);
  return v;
}
// reduce within groups of 16 consecutive lanes
__device__ __forceinline__ float wsum16(float v) {
  v += __shfl_xor(v, 1, 64);
  v += __shfl_xor(v, 2, 64);
  v += __shfl_xor(v, 4, 64);
  v += __shfl_xor(v, 8, 64);
  return v;
}

__device__ __forceinline__ float frcp(float x) { return __builtin_amdgcn_rcpf(x); }
__device__ __forceinline__ float fexp(float x) { return __expf(x); }
__device__ __forceinline__ float flog(float x) { return __logf(x); }
__device__ __forceinline__ float ftanh_pos(float x) {  // tanh, x >= 0
  float e = fexp(2.f * x);
  return 1.f - 2.f * frcp(e + 1.f);
}
__device__ __forceinline__ float fatanh01(float t) {  // atanh, t in [0,1)
  return 0.5f * flog((1.f + t) * frcp(1.f - t));
}

__device__ __forceinline__ void gload16(const void* g, void* lds) {
  __builtin_amdgcn_global_load_lds(
      (const __attribute__((address_space(1))) uint32_t*)(uintptr_t)g,
      (__attribute__((address_space(3))) uint32_t*)(uintptr_t)lds, 16, 0, 0);
}

struct EpiArgs {
  const float* sb;     // [16][64] projected mobius bias per head
  const float* y2;     // [16] sbn^2 per head
  const float* c_st;   // stereo curvature (c_v or c_ff)
  const float* c_at;   // attention curvature (V mode)
  const float* mask;   // [NTOK] (V mode)
  half_t* Qh;          // V mode: in-place Q -> v1
  half_t* Kh;          // V mode: in-place K -> v2
  half_t* xh;          // V mode: out x
  float* v2sum;        // V mode: [16][64] atomics
};

// =============== GEMM: C[M,N] = A[M,K](f16) * (Bh+Bl)[N,K]^T ==============
// 128x128 tile, BK=64, 256 thr, per-wave 4x4 grid of 16x16x32 f16 MFMAs,
// 2 MFMAs per tile (B hi + B lo) into the same accumulator.
// Each wave's epilogue region = 64 rows x 64 cols = one full head.
// MODE 0: plain f16 out + bias. MODE 1: fused stereo + attn-pass1 (V).
// MODE 2: fused stereo -> fp32 out (FF, final output).
template <int MODE, typename OutT>
__global__ __launch_bounds__(256, 3) void gemm_f16(const half_t* __restrict__ A,
                                                   const half_t* __restrict__ Bh,
                                                   const half_t* __restrict__ Bl,
                                                   const float* __restrict__ bias,
                                                   OutT* __restrict__ C,
                                                   int M, int Nn, int K, EpiArgs ep) {
  __shared__ half_t sA[128 * 64];
  __shared__ half_t sBh[128 * 64];
  __shared__ half_t sBl[128 * 64];
  const int tid = threadIdx.x;
  const int lane = tid & 63;
  const int w = tid >> 6;
  const int n0 = blockIdx.x * 128;
  const int m0 = blockIdx.y * 128;

  const half_t* srcA[4];
  const half_t* srcBh[4];
  const half_t* srcBl[4];
  int dstOff[4];
#pragma unroll
  for (int t = 0; t < 4; ++t) {
    int idx = w * 4 + t;
    int ks = idx >> 3, g = idx & 7;
    int row = g * 16 + (lane & 15);
    int kof = ks * 32 + (lane >> 4) * 8;
    srcA[t] = A + (size_t)(m0 + row) * K + kof;
    srcBh[t] = Bh + (size_t)(n0 + row) * K + kof;
    srcBl[t] = Bl + (size_t)(n0 + row) * K + kof;
    dstOff[t] = (ks * 8 + g) * 512;
  }

  floatx4 acc[4][4];
#pragma unroll
  for (int i = 0; i < 4; ++i)
#pragma unroll
    for (int j = 0; j < 4; ++j) acc[i][j] = (floatx4){0.f, 0.f, 0.f, 0.f};

  const int wr = (w >> 1) * 4;
  const int wc = (w & 1) * 4;

  for (int k0 = 0; k0 < K; k0 += 64) {
#pragma unroll
    for (int t = 0; t < 4; ++t) {
      gload16(srcA[t], sA + dstOff[t]);
      gload16(srcBh[t], sBh + dstOff[t]);
      gload16(srcBl[t], sBl + dstOff[t]);
      srcA[t] += 64;
      srcBh[t] += 64;
      srcBl[t] += 64;
    }
    __syncthreads();
#pragma unroll
    for (int ks = 0; ks < 2; ++ks) {
      half8 af[4], bhf[4], blf[4];
#pragma unroll
      for (int i = 0; i < 4; ++i)
        af[i] = *(const half8*)&sA[(ks * 8 + wr + i) * 512 + lane * 8];
#pragma unroll
      for (int j = 0; j < 4; ++j) {
        bhf[j] = *(const half8*)&sBh[(ks * 8 + wc + j) * 512 + lane * 8];
        blf[j] = *(const half8*)&sBl[(ks * 8 + wc + j) * 512 + lane * 8];
      }
#pragma unroll
      for (int i = 0; i < 4; ++i)
#pragma unroll
        for (int j = 0; j < 4; ++j) {
          acc[i][j] = __builtin_amdgcn_mfma_f32_16x16x32_f16(af[i], bhf[j], acc[i][j], 0, 0, 0);
          acc[i][j] = __builtin_amdgcn_mfma_f32_16x16x32_f16(af[i], blf[j], acc[i][j], 0, 0, 0);
        }
    }
    __syncthreads();
  }

  const int e = lane & 15;
  const int quad = lane >> 4;

  if constexpr (MODE == 0) {
#pragma unroll
    for (int j = 0; j < 4; ++j) {
      int col = n0 + (w & 1) * 64 + j * 16 + e;
      float bv = bias ? bias[col] : 0.f;
#pragma unroll
      for (int i = 0; i < 4; ++i) {
        int row = m0 + (w >> 1) * 64 + i * 16 + quad * 4;
#pragma unroll
        for (int r = 0; r < 4; ++r)
          C[(size_t)(row + r) * Nn + col] = (OutT)(acc[i][j][r] + bv);
      }
    }
  } else {
    const int hb = n0 + (w & 1) * 64;  // head base col
    const int h = hb >> 6;
    const float kst = ep.c_st[h];
    const float sk = sqrtf(fmaxf(fabsf(kst), 1e-15f));
    const float rsk = frcp(sk);
    const float maxn = (1.f - 1e-5f) * rsk;
    const float mx2 = maxn * maxn;
    float sbj[4];
#pragma unroll
    for (int j = 0; j < 4; ++j) sbj[j] = ep.sb[hb + j * 16 + e];
    const float y2h = ep.y2[h];
    float ka = 0.f, v2acc[4] = {0.f, 0.f, 0.f, 0.f};
    if constexpr (MODE == 1) ka = ep.c_at[h];
    const int rowbase = m0 + (w >> 1) * 64;

#pragma unroll
    for (int i = 0; i < 4; ++i) {
#pragma unroll
      for (int r = 0; r < 4; ++r) {
        const int row = rowbase + i * 16 + quad * 4 + r;
        float s = 0.f, dp = 0.f;
#pragma unroll
        for (int j = 0; j < 4; ++j) {
          float mv = acc[i][j][r];
          s += mv * mv;
          dp += mv * sbj[j];
        }
        s = wsum16(s);
        dp = wsum16(dp);
        // expmap0 + project
        float un = fmaxf(sqrtf(s), 1e-15f);
        float tn = ftanh_pos(un * sk) * rsk;
        float f = tn * frcp(un);
        float rn = fmaxf(tn, 1e-15f);
        if (rn > maxn) { f *= maxn * frcp(rn); rn = maxn; }
        // mobius_add(v, sb) + project
        float xy = dp * f;
        float x2 = rn * rn;
        float num1 = 1.f - 2.f * kst * xy - kst * y2h;
        float num2 = 1.f + kst * x2;
        float den = fmaxf(1.f - 2.f * kst * xy + kst * kst * x2 * y2h, 1e-15f);
        float rden = frcp(den);
        float c1 = num1 * f * rden;
        float c2 = num2 * rden;
        float o[4];
        float os = 0.f;
#pragma unroll
        for (int j = 0; j < 4; ++j) {
          o[j] = c1 * acc[i][j][r] + c2 * sbj[j];
          os += o[j] * o[j];
        }
        os = wsum16(os);
        float on = fmaxf(sqrtf(os), 1e-15f);
        if (on > maxn) {
          float sc = maxn * frcp(on);
#pragma unroll
          for (int j = 0; j < 4; ++j) o[j] *= sc;
        }
        if constexpr (MODE == 2) {
#pragma unroll
          for (int j = 0; j < 4; ++j)
            C[(size_t)row * Nn + hb + j * 16 + e] = (OutT)o[j];
        } else {
          // fused attn pass 1
          float vn2 = fminf(os, mx2);
          float pt = fmaxf(1.f + ka * vn2, 1e-15f);
          float rpt = frcp(pt);
          float gamma = fmaxf(2.f * rpt, 1e-15f);
          float gm1 = gamma - 1.f;
          float aden = fmaxf(fabsf(gm1), 1e-10f);
          float den2 = (gm1 >= 0.f) ? aden : -aden;
          float mrow = ep.mask[row];
          float xsc = gamma * frcp(den2) * mrow;
          size_t rb = (size_t)row * Nn + hb + e;
#pragma unroll
          for (int j = 0; j < 4; ++j) {
            size_t gi = rb + j * 16;
            float q = (float)ep.Qh[gi] * rpt;
            float v1 = (q > 0.f) ? (q + 1.f) : fexp(q);
            ep.Qh[gi] = (half_t)v1;
            float kv = (float)ep.Kh[gi] * rpt;
            float v2 = den2 * ((kv > 0.f) ? (kv + 1.f) : fexp(kv)) * mrow;
            ep.Kh[gi] = (half_t)v2;
            v2acc[j] += v2;
            ep.xh[gi] = (half_t)(xsc * o[j]);
          }
        }
      }
    }
    if constexpr (MODE == 1) {
#pragma unroll
      for (int j = 0; j < 4; ++j) {
        float t = v2acc[j];
        t += __shfl_xor(t, 16, 64);
        t += __shfl_xor(t, 32, 64);
        if (quad == 0) atomicAdd(&ep.v2sum[h * DHD + j * 16 + e], t);
      }
    }
  }
}

// =============== weight split fp32 -> f16 hi + f16 lo =====================
struct WPack {
  const float* w[4];
  half_t* h[4];
  half_t* l[4];
};
__global__ __launch_bounds__(256) void convert_w_kernel(WPack pk) {
  int wi = blockIdx.y;
  const float* w = pk.w[wi];
  half_t* ph = pk.h[wi];
  half_t* pl = pk.l[wi];
  int i = (blockIdx.x * 256 + threadIdx.x) * 4;
  float4 v = *(const float4*)&w[i];
  half4 hh, ll;
  hh.x = (half_t)v.x; ll.x = (half_t)(v.x - (float)hh.x);
  hh.y = (half_t)v.y; ll.y = (half_t)(v.y - (float)hh.y);
  hh.z = (half_t)v.z; ll.z = (half_t)(v.z - (float)hh.z);
  hh.w = (half_t)v.w; ll.w = (half_t)(v.w - (float)hh.w);
  *(half4*)&ph[i] = hh;
  *(half4*)&pl[i] = ll;
}

// ====== precompute projected mobius bias sb per head (V and FF sets) ======
__global__ __launch_bounds__(128) void prep_sb_kernel(const float* __restrict__ bv,
                                                      const float* __restrict__ cv,
                                                      const float* __restrict__ bf,
                                                      const float* __restrict__ cf,
                                                      float* __restrict__ sbV,
                                                      float* __restrict__ y2V,
                                                      float* __restrict__ sbF,
                                                      float* __restrict__ y2F) {
  int wv = threadIdx.x >> 6;
  int lane = threadIdx.x & 63;
  const float* b = wv ? bf : bv;
  const float* c = wv ? cf : cv;
  float* sb = wv ? sbF : sbV;
  float* y2 = wv ? y2F : y2V;
  for (int h = 0; h < NH; ++h) {
    float k = c[h];
    float sk = sqrtf(fmaxf(fabsf(k), 1e-15f));
    float rsk = frcp(sk);
    float maxn = (1.f - 1e-5f) * rsk;
    float bb = b[h * DHD + lane];
    float bs = wsum(bb * bb);
    float bn = fmaxf(sqrtf(bs), 1e-15f);
    float tb = ftanh_pos(bn * sk) * rsk;
    float sv = tb * frcp(bn) * bb;
    float sbn = fmaxf(tb, 1e-15f);
    if (sbn > maxn) { sv *= maxn * frcp(sbn); sbn = maxn; }
    sb[h * DHD + lane] = sv;
    if (lane == 0) y2[h] = sbn * sbn;
  }
}

// =============== prep: Xh = f16(X); U = f16(logmap0(X, c_v)) ==============
// float4/lane, 16 lanes per head, wsum16 reductions.
__global__ __launch_bounds__(256) void prep_kernel(const float* __restrict__ X,
                                                   half_t* __restrict__ Xh,
                                                   half_t* __restrict__ U,
                                                   const float* __restrict__ c) {
  int lane = threadIdx.x & 63;
  int wid = blockIdx.x * 4 + (threadIdx.x >> 6);
  int nw = gridDim.x * 4;
  int sub = lane >> 4;
  for (int row = wid; row < NTOK; row += nw) {
#pragma unroll
    for (int ch = 0; ch < 4; ++ch) {
      int h = ch * 4 + sub;
      int idx = row * DIMF + ch * 256 + lane * 4;
      float4 x = *(const float4*)&X[idx];
      float s = x.x * x.x + x.y * x.y + x.z * x.z + x.w * x.w;
      s = wsum16(s);
      float k = c[h];
      float sk = sqrtf(fmaxf(fabsf(k), 1e-15f));
      float yn = fmaxf(sqrtf(s), 1e-15f);
      float t = fminf(yn * sk, 1.f - 1e-7f);
      float f = fatanh01(t) * frcp(sk) * frcp(yn);
      half4 xh4 = {(half_t)x.x, (half_t)x.y, (half_t)x.z, (half_t)x.w};
      *(half4*)&Xh[idx] = xh4;
      half4 u4 = {(half_t)(x.x * f), (half_t)(x.y * f), (half_t)(x.z * f), (half_t)(x.w * f)};
      *(half4*)&U[idx] = u4;
    }
  }
}

// ======= pass 2: ctxT[h][e][d] = sum_n v2h[n,h,d]*xh[n,h,e] ===============
#define TOK2 512
__global__ __launch_bounds__(256) void attn_pass2(const half_t* __restrict__ v2h,
                                                  const half_t* __restrict__ xh,
                                                  float* __restrict__ ctxT) {
  __shared__ float v2s[16][64];
  __shared__ float xs[16][64];
  int tid = threadIdx.x;
  int h = blockIdx.y;
  int n0 = blockIdx.x * TOK2;
  int e = tid & 63;
  int dg = tid >> 6;  // wave-uniform
  int ltt = tid >> 4;
  int lcol = (tid & 15) * 4;
  float acc[16];
#pragma unroll
  for (int i = 0; i < 16; ++i) acc[i] = 0.f;
  for (int t = 0; t < TOK2; t += 16) {
    __syncthreads();
    size_t g = (size_t)(n0 + t + ltt) * DIMF + h * DHD + lcol;
    half4 a = *(const half4*)&v2h[g];
    half4 b = *(const half4*)&xh[g];
    *(float4*)&v2s[ltt][lcol] = make_float4((float)a.x, (float)a.y, (float)a.z, (float)a.w);
    *(float4*)&xs[ltt][lcol] = make_float4((float)b.x, (float)b.y, (float)b.z, (float)b.w);
    __syncthreads();
#pragma unroll
    for (int tt = 0; tt < 16; ++tt) {
      float xv = xs[tt][e];
      float4 p0 = *(const float4*)&v2s[tt][dg * 16 + 0];
      float4 p1 = *(const float4*)&v2s[tt][dg * 16 + 4];
      float4 p2 = *(const float4*)&v2s[tt][dg * 16 + 8];
      float4 p3 = *(const float4*)&v2s[tt][dg * 16 + 12];
      acc[0] = fmaf(p0.x, xv, acc[0]);   acc[1] = fmaf(p0.y, xv, acc[1]);
      acc[2] = fmaf(p0.z, xv, acc[2]);   acc[3] = fmaf(p0.w, xv, acc[3]);
      acc[4] = fmaf(p1.x, xv, acc[4]);   acc[5] = fmaf(p1.y, xv, acc[5]);
      acc[6] = fmaf(p1.z, xv, acc[6]);   acc[7] = fmaf(p1.w, xv, acc[7]);
      acc[8] = fmaf(p2.x, xv, acc[8]);   acc[9] = fmaf(p2.y, xv, acc[9]);
      acc[10] = fmaf(p2.z, xv, acc[10]); acc[11] = fmaf(p2.w, xv, acc[11]);
      acc[12] = fmaf(p3.x, xv, acc[12]); acc[13] = fmaf(p3.y, xv, acc[13]);
      acc[14] = fmaf(p3.z, xv, acc[14]); acc[15] = fmaf(p3.w, xv, acc[15]);
    }
  }
#pragma unroll
  for (int i = 0; i < 16; ++i)
    atomicAdd(&ctxT[h * 4096 + e * 64 + dg * 16 + i], acc[i]);
}

// ======= pass 3 (MFMA): Xo = Dinv * (v1h @ ctx), fused Dinv + mobius epi
__global__ __launch_bounds__(256) void attn_pass3m(const half_t* __restrict__ v1h,
                                                   const float* __restrict__ ctxT,
                                                   const float* __restrict__ v2sum,
                                                   const float* __restrict__ c_at,
                                                   const float* __restrict__ c_ff,
                                                   half_t* __restrict__ Uff) {
  __shared__ half_t sctx[8 * 64 * 8];
  int tid = threadIdx.x;
  int h = blockIdx.y;
  int m0 = blockIdx.x * 64;
  for (int ci = tid; ci < 512; ci += 256) {
    int t = ci >> 6, l = ci & 63;
    int j = t & 3, ks = t >> 2;
    int e2 = j * 16 + (l & 15);
    int d = ks * 32 + (l >> 4) * 8;
    const float* src = &ctxT[h * 4096 + e2 * 64 + d];
    half8 hh;
#pragma unroll
    for (int q = 0; q < 8; ++q) hh[q] = (half_t)src[q];
    *(half8*)&sctx[ci * 8] = hh;
  }
  __syncthreads();

  int lane = tid & 63;
  int w = tid >> 6;
  int quad = lane >> 4;
  int e = lane & 15;

  const half_t* ap = v1h + (size_t)(m0 + w * 16 + e) * DIMF + h * DHD + quad * 8;
  half8 a0 = *(const half8*)ap;
  half8 a1 = *(const half8*)(ap + 32);

  // fused Dinv: dot(v1[row,:], v2sum[h,:])
  const float* vsp = v2sum + h * DHD + quad * 8;
  float4 va = *(const float4*)&vsp[0];
  float4 vb = *(const float4*)&vsp[4];
  float4 vc = *(const float4*)&vsp[32];
  float4 vd = *(const float4*)&vsp[36];
  float dn = (float)a0[0] * va.x + (float)a0[1] * va.y + (float)a0[2] * va.z + (float)a0[3] * va.w +
             (float)a0[4] * vb.x + (float)a0[5] * vb.y + (float)a0[6] * vb.z + (float)a0[7] * vb.w +
             (float)a1[0] * vc.x + (float)a1[1] * vc.y + (float)a1[2] * vc.z + (float)a1[3] * vc.w +
             (float)a1[4] * vd.x + (float)a1[5] * vd.y + (float)a1[6] * vd.z + (float)a1[7] * vd.w;
  dn += __shfl_xor(dn, 16, 64);
  dn += __shfl_xor(dn, 32, 64);
  float di = frcp((dn == 0.f) ? 1e-5f : dn);

  floatx4 acc[4];
#pragma unroll
  for (int j = 0; j < 4; ++j) acc[j] = (floatx4){0.f, 0.f, 0.f, 0.f};
#pragma unroll
  for (int j = 0; j < 4; ++j) {
    half8 b0 = *(const half8*)&sctx[((0 * 4 + j) * 64 + lane) * 8];
    half8 b1 = *(const half8*)&sctx[((1 * 4 + j) * 64 + lane) * 8];
    acc[j] = __builtin_amdgcn_mfma_f32_16x16x32_f16(a0, b0, acc[j], 0, 0, 0);
    acc[j] = __builtin_amdgcn_mfma_f32_16x16x32_f16(a1, b1, acc[j], 0, 0, 0);
  }

  float ka = c_at[h];
  float sk_a = sqrtf(fmaxf(fabsf(ka), 1e-15f));
  float rsk_a = frcp(sk_a);
  float maxn_a = (1.f - 1e-5f) * rsk_a;
  float kf = c_ff[h];
  float sk_f = sqrtf(fmaxf(fabsf(kf), 1e-15f));
  float rsk_f = frcp(sk_f);

#pragma unroll
  for (int r = 0; r < 4; ++r) {
    float Di = __shfl(di, quad * 4 + r, 64);
    float v0 = acc[0][r], v1 = acc[1][r], v2 = acc[2][r], v3 = acc[3][r];
    float s = v0 * v0 + v1 * v1 + v2 * v2 + v3 * v3;
    s = wsum16(s);
    int row = m0 + w * 16 + quad * 4 + r;
    float f = Di;
    float xn = fmaxf(sqrtf(s) * Di, 1e-15f);
    if (xn > maxn_a) { f *= maxn_a * frcp(xn); xn = maxn_a; }
    float t = fminf(xn * sk_a, 1.f - 1e-7f);
    float ar = fatanh01(t) * rsk_a;
    float tk = ftanh_pos(0.5f * ar * sk_a) * rsk_a;
    f *= tk * frcp(xn);
    float nn = tk;
    if (nn > maxn_a) { f *= maxn_a * frcp(nn); nn = maxn_a; }
    float fn = fmaxf(nn, 1e-15f);
    float t2 = fminf(fn * sk_f, 1.f - 1e-7f);
    float ar2 = fatanh01(t2) * rsk_f;
    f *= ar2 * frcp(fn);
    size_t base = (size_t)row * DIMF + h * DHD + e;
    Uff[base + 0] = (half_t)(v0 * f);
    Uff[base + 16] = (half_t)(v1 * f);
    Uff[base + 32] = (half_t)(v2 * f);
    Uff[base + 48] = (half_t)(v3 * f);
  }
}

extern "C" void kernel_launch(void* const* d_in, const int* in_sizes, int n_in,
                              void* d_out, int out_size, void* d_ws, size_t ws_size,
                              hipStream_t stream) {
  const float* X = (const float*)d_in[0];
  const float* mask = (const float*)d_in[1];
  const float* Wq = (const float*)d_in[2];
  const float* bq = (const float*)d_in[3];
  const float* Wk = (const float*)d_in[4];
  const float* bk = (const float*)d_in[5];
  const float* Wv = (const float*)d_in[6];
  const float* bv = (const float*)d_in[7];
  const float* c_v = (const float*)d_in[8];
  const float* c_at = (const float*)d_in[9];
  const float* Wff = (const float*)d_in[10];
  const float* bff = (const float*)d_in[11];
  const float* c_ff = (const float*)d_in[12];
  float* out = (float*)d_out;

  const size_t NE = (size_t)NTOK * DIMF;
  float* v2sum = (float*)d_ws;         // 1024
  float* ctxT = v2sum + 1024;          // 65536
  float* sbV = ctxT + 65536;           // 1024
  float* sbF = sbV + 1024;             // 1024
  float* y2V = sbF + 1024;             // 16
  float* y2F = y2V + 16;               // 16
  half_t* H1 = (half_t*)(y2F + 16);    // Xh -> Uff
  half_t* H2 = H1 + NE;                // Uv
  half_t* H3 = H2 + NE;                // Kh -> v2h
  half_t* H4 = H3 + NE;                // Qh -> v1h
  half_t* H5 = H4 + NE;                // xh
  half_t* Wh0 = H5 + NE;
  half_t* Wl0 = Wh0 + 4 * (size_t)DIMF * DIMF;

  WPack pk;
  pk.w[0] = Wq; pk.w[1] = Wk; pk.w[2] = Wv; pk.w[3] = Wff;
  for (int i = 0; i < 4; ++i) {
    pk.h[i] = Wh0 + (size_t)i * DIMF * DIMF;
    pk.l[i] = Wl0 + (size_t)i * DIMF * DIMF;
  }

  dim3 gg(DIMF / 128, NTOK / 128);
  EpiArgs epN{};  // unused for MODE 0
  EpiArgs epV{sbV, y2V, c_v, c_at, mask, H4, H3, H5, v2sum};
  EpiArgs epF{sbF, y2F, c_ff, nullptr, nullptr, nullptr, nullptr, nullptr, nullptr};

  convert_w_kernel<<<dim3(1024, 4), 256, 0, stream>>>(pk);
  prep_sb_kernel<<<1, 128, 0, stream>>>(bv, c_v, bff, c_ff, sbV, y2V, sbF, y2F);
  prep_kernel<<<512, 256, 0, stream>>>(X, H1, H2, c_v);
  hipMemsetAsync(v2sum, 0, (1024 + 65536) * sizeof(float), stream);
  // Q, K (plain f16 + bias)
  gemm_f16<0, half_t><<<gg, 256, 0, stream>>>(H1, pk.h[0], pk.l[0], bq, H4, NTOK, DIMF, DIMF, epN);
  gemm_f16<0, half_t><<<gg, 256, 0, stream>>>(H1, pk.h[1], pk.l[1], bk, H3, NTOK, DIMF, DIMF, epN);
  // V with fused stereo + attention pass 1
  gemm_f16<1, half_t><<<gg, 256, 0, stream>>>(H2, pk.h[2], pk.l[2], nullptr, (half_t*)nullptr, NTOK, DIMF, DIMF, epV);
  // attention core
  attn_pass2<<<dim3(NTOK / TOK2, NH), 256, 0, stream>>>(H3, H5, ctxT);
  attn_pass3m<<<dim3(NTOK / 64, NH), 256, 0, stream>>>(H4, ctxT, v2sum, c_at, c_ff, H1);
  // FF with fused stereo -> final fp32 out
  gemm_f16<2, float><<<gg, 256, 0, stream>>>(H1, pk.h[3], pk.l[3], nullptr, out, NTOK, DIMF, DIMF, epF);
}

// Round 4
// 653.284 us; speedup vs baseline: 4.3472x; 1.2985x over previous
//
#include <hip/hip_runtime.h>
#include <math.h>
#include <stdint.h>

#define NTOK 16384
#define DIMF 1024
#define NH 16
#define DHD 64
#define NQK 2048

typedef _Float16 half_t;
typedef __attribute__((ext_vector_type(8))) _Float16 half8;
typedef __attribute__((ext_vector_type(4))) _Float16 half4;
typedef __attribute__((ext_vector_type(4))) float floatx4;

__device__ __forceinline__ float wsum(float v) {
  v += __shfl_xor(v, 32, 64);
  v += __shfl_xor(v, 16, 64);
  v += __shfl_xor(v, 8, 64);
  v += __shfl_xor(v, 4, 64);
  v += __shfl_xor(v, 2, 64);
  v += __shfl_xor(v, 1, 64);
  return v;
}
__device__ __forceinline__ float wsum16(float v) {
  v += __shfl_xor(v, 1, 64);
  v += __shfl_xor(v, 2, 64);
  v += __shfl_xor(v, 4, 64);
  v += __shfl_xor(v, 8, 64);
  return v;
}

__device__ __forceinline__ float frcp(float x) { return __builtin_amdgcn_rcpf(x); }
__device__ __forceinline__ float fexp(float x) { return __expf(x); }
__device__ __forceinline__ float flog(float x) { return __logf(x); }
__device__ __forceinline__ float ftanh_pos(float x) {  // tanh, x >= 0
  float e = fexp(2.f * x);
  return 1.f - 2.f * frcp(e + 1.f);
}
__device__ __forceinline__ float fatanh01(float t) {  // atanh, t in [0,1)
  return 0.5f * flog((1.f + t) * frcp(1.f - t));
}

__device__ __forceinline__ void gload16(const void* g, void* lds) {
  __builtin_amdgcn_global_load_lds(
      (const __attribute__((address_space(1))) uint32_t*)(uintptr_t)g,
      (__attribute__((address_space(3))) uint32_t*)(uintptr_t)lds, 16, 0, 0);
}

struct EpiArgs {
  const float* sb;     // [16][64] projected mobius bias per head
  const float* y2;     // [16] sbn^2 per head
  const float* c_st;   // stereo curvature (c_v or c_ff)
  const float* c_at;   // attention curvature (V mode)
  const float* mask;   // [NTOK] (V mode)
  half_t* Qh;          // V mode: in-place Q -> v1 (stride qstride)
  half_t* Kh;          // V mode: in-place K -> v2 (stride qstride)
  half_t* xh;          // V mode: out x (stride Nn)
  float* v2sum;        // V mode: [16][64] atomics
  int qstride;         // row stride of Qh/Kh
};

// =============== GEMM: C[M,N] = A[M,K](f16) * B[N,K]^T(f16) ===============
// 128x128 tile, BK=64, 256 thr, per-wave 4x4 grid of 16x16x32 f16 MFMAs.
// LDS fragment-canonical: 1KB blocks of 64 chunks x 16B, chunk idx == lane.
// Each wave's epilogue region = 64 rows x 64 cols = one full head.
// MODE 0: plain f16 out + bias. MODE 1: fused stereo + attn-pass1 (V).
// MODE 2: fused stereo -> fp32 out (FF, final output).
template <int MODE, typename OutT>
__global__ __launch_bounds__(256, 4) void gemm_f16(const half_t* __restrict__ A,
                                                   const half_t* __restrict__ B,
                                                   const float* __restrict__ bias,
                                                   OutT* __restrict__ C,
                                                   int M, int Nn, int K, EpiArgs ep) {
  __shared__ half_t sA[128 * 64];
  __shared__ half_t sB[128 * 64];
  const int tid = threadIdx.x;
  const int lane = tid & 63;
  const int w = tid >> 6;
  const int n0 = blockIdx.x * 128;
  const int m0 = blockIdx.y * 128;

  const half_t* srcA[4];
  const half_t* srcB[4];
  int dstOff[4];
#pragma unroll
  for (int t = 0; t < 4; ++t) {
    int idx = w * 4 + t;
    int ks = idx >> 3, g = idx & 7;
    int row = g * 16 + (lane & 15);
    int kof = ks * 32 + (lane >> 4) * 8;
    srcA[t] = A + (size_t)(m0 + row) * K + kof;
    srcB[t] = B + (size_t)(n0 + row) * K + kof;
    dstOff[t] = (ks * 8 + g) * 512;
  }

  floatx4 acc[4][4];
#pragma unroll
  for (int i = 0; i < 4; ++i)
#pragma unroll
    for (int j = 0; j < 4; ++j) acc[i][j] = (floatx4){0.f, 0.f, 0.f, 0.f};

  const int wr = (w >> 1) * 4;
  const int wc = (w & 1) * 4;

  for (int k0 = 0; k0 < K; k0 += 64) {
#pragma unroll
    for (int t = 0; t < 4; ++t) {
      gload16(srcA[t], sA + dstOff[t]);
      gload16(srcB[t], sB + dstOff[t]);
      srcA[t] += 64;
      srcB[t] += 64;
    }
    __syncthreads();
#pragma unroll
    for (int ks = 0; ks < 2; ++ks) {
      half8 af[4], bf[4];
#pragma unroll
      for (int i = 0; i < 4; ++i)
        af[i] = *(const half8*)&sA[(ks * 8 + wr + i) * 512 + lane * 8];
#pragma unroll
      for (int j = 0; j < 4; ++j)
        bf[j] = *(const half8*)&sB[(ks * 8 + wc + j) * 512 + lane * 8];
#pragma unroll
      for (int i = 0; i < 4; ++i)
#pragma unroll
        for (int j = 0; j < 4; ++j)
          acc[i][j] = __builtin_amdgcn_mfma_f32_16x16x32_f16(af[i], bf[j], acc[i][j], 0, 0, 0);
    }
    __syncthreads();
  }

  const int e = lane & 15;
  const int quad = lane >> 4;

  if constexpr (MODE == 0) {
#pragma unroll
    for (int j = 0; j < 4; ++j) {
      int col = n0 + (w & 1) * 64 + j * 16 + e;
      float bv = bias ? bias[col] : 0.f;
#pragma unroll
      for (int i = 0; i < 4; ++i) {
        int row = m0 + (w >> 1) * 64 + i * 16 + quad * 4;
#pragma unroll
        for (int r = 0; r < 4; ++r)
          C[(size_t)(row + r) * Nn + col] = (OutT)(acc[i][j][r] + bv);
      }
    }
  } else {
    const int hb = n0 + (w & 1) * 64;  // head base col
    const int h = hb >> 6;
    const float kst = ep.c_st[h];
    const float sk = sqrtf(fmaxf(fabsf(kst), 1e-15f));
    const float rsk = frcp(sk);
    const float maxn = (1.f - 1e-5f) * rsk;
    const float mx2 = maxn * maxn;
    float sbj[4];
#pragma unroll
    for (int j = 0; j < 4; ++j) sbj[j] = ep.sb[hb + j * 16 + e];
    const float y2h = ep.y2[h];
    float ka = 0.f, v2acc[4] = {0.f, 0.f, 0.f, 0.f};
    if constexpr (MODE == 1) ka = ep.c_at[h];
    const int rowbase = m0 + (w >> 1) * 64;

#pragma unroll
    for (int i = 0; i < 4; ++i) {
#pragma unroll
      for (int r = 0; r < 4; ++r) {
        const int row = rowbase + i * 16 + quad * 4 + r;
        float s = 0.f, dp = 0.f;
#pragma unroll
        for (int j = 0; j < 4; ++j) {
          float mv = acc[i][j][r];
          s += mv * mv;
          dp += mv * sbj[j];
        }
        s = wsum16(s);
        dp = wsum16(dp);
        // expmap0 + project
        float un = fmaxf(sqrtf(s), 1e-15f);
        float tn = ftanh_pos(un * sk) * rsk;
        float f = tn * frcp(un);
        float rn = fmaxf(tn, 1e-15f);
        if (rn > maxn) { f *= maxn * frcp(rn); rn = maxn; }
        // mobius_add(v, sb) + project
        float xy = dp * f;
        float x2 = rn * rn;
        float num1 = 1.f - 2.f * kst * xy - kst * y2h;
        float num2 = 1.f + kst * x2;
        float den = fmaxf(1.f - 2.f * kst * xy + kst * kst * x2 * y2h, 1e-15f);
        float rden = frcp(den);
        float c1 = num1 * f * rden;
        float c2 = num2 * rden;
        float o[4];
        float os = 0.f;
#pragma unroll
        for (int j = 0; j < 4; ++j) {
          o[j] = c1 * acc[i][j][r] + c2 * sbj[j];
          os += o[j] * o[j];
        }
        os = wsum16(os);
        float on = fmaxf(sqrtf(os), 1e-15f);
        if (on > maxn) {
          float sc = maxn * frcp(on);
#pragma unroll
          for (int j = 0; j < 4; ++j) o[j] *= sc;
        }
        if constexpr (MODE == 2) {
#pragma unroll
          for (int j = 0; j < 4; ++j)
            C[(size_t)row * Nn + hb + j * 16 + e] = (OutT)o[j];
        } else {
          // fused attn pass 1
          float vn2 = fminf(os, mx2);
          float pt = fmaxf(1.f + ka * vn2, 1e-15f);
          float rpt = frcp(pt);
          float gamma = fmaxf(2.f * rpt, 1e-15f);
          float gm1 = gamma - 1.f;
          float aden = fmaxf(fabsf(gm1), 1e-10f);
          float den2 = (gm1 >= 0.f) ? aden : -aden;
          float mrow = ep.mask[row];
          float xsc = gamma * frcp(den2) * mrow;
          size_t qb = (size_t)row * ep.qstride + hb + e;
          size_t xb = (size_t)row * Nn + hb + e;
#pragma unroll
          for (int j = 0; j < 4; ++j) {
            size_t gi = qb + j * 16;
            float q = (float)ep.Qh[gi] * rpt;
            float v1 = (q > 0.f) ? (q + 1.f) : fexp(q);
            ep.Qh[gi] = (half_t)v1;
            float kv = (float)ep.Kh[gi] * rpt;
            float v2 = den2 * ((kv > 0.f) ? (kv + 1.f) : fexp(kv)) * mrow;
            ep.Kh[gi] = (half_t)v2;
            v2acc[j] += v2;
            ep.xh[xb + j * 16] = (half_t)(xsc * o[j]);
          }
        }
      }
    }
    if constexpr (MODE == 1) {
#pragma unroll
      for (int j = 0; j < 4; ++j) {
        float t = v2acc[j];
        t += __shfl_xor(t, 16, 64);
        t += __shfl_xor(t, 32, 64);
        if (quad == 0) atomicAdd(&ep.v2sum[h * DHD + j * 16 + e], t);
      }
    }
  }
}

// =============== weight convert fp32 -> f16 (no split) ====================
struct WPack {
  const float* w[4];
  half_t* h[4];
};
__global__ __launch_bounds__(256) void convert_w_kernel(WPack pk) {
  int wi = blockIdx.y;
  const float* w = pk.w[wi];
  half_t* ph = pk.h[wi];
  int i = (blockIdx.x * 256 + threadIdx.x) * 4;
  float4 v = *(const float4*)&w[i];
  half4 hh = {(half_t)v.x, (half_t)v.y, (half_t)v.z, (half_t)v.w};
  *(half4*)&ph[i] = hh;
}

// ====== precompute projected mobius bias sb per head + combined QK bias ===
__global__ __launch_bounds__(128) void prep_sb_kernel(const float* __restrict__ bv,
                                                      const float* __restrict__ cv,
                                                      const float* __restrict__ bf,
                                                      const float* __restrict__ cf,
                                                      const float* __restrict__ bq,
                                                      const float* __restrict__ bk,
                                                      float* __restrict__ sbV,
                                                      float* __restrict__ y2V,
                                                      float* __restrict__ sbF,
                                                      float* __restrict__ y2F,
                                                      float* __restrict__ bqk) {
  int tid = threadIdx.x;
  for (int i = tid; i < 1024; i += 128) {
    bqk[i] = bq[i];
    bqk[1024 + i] = bk[i];
  }
  int wv = tid >> 6;
  int lane = tid & 63;
  const float* b = wv ? bf : bv;
  const float* c = wv ? cf : cv;
  float* sb = wv ? sbF : sbV;
  float* y2 = wv ? y2F : y2V;
  for (int h = 0; h < NH; ++h) {
    float k = c[h];
    float sk = sqrtf(fmaxf(fabsf(k), 1e-15f));
    float rsk = frcp(sk);
    float maxn = (1.f - 1e-5f) * rsk;
    float bb = b[h * DHD + lane];
    float bs = wsum(bb * bb);
    float bn = fmaxf(sqrtf(bs), 1e-15f);
    float tb = ftanh_pos(bn * sk) * rsk;
    float sv = tb * frcp(bn) * bb;
    float sbn = fmaxf(tb, 1e-15f);
    if (sbn > maxn) { sv *= maxn * frcp(sbn); sbn = maxn; }
    sb[h * DHD + lane] = sv;
    if (lane == 0) y2[h] = sbn * sbn;
  }
}

// =============== prep: Xh = f16(X); U = f16(logmap0(X, c_v)) ==============
__global__ __launch_bounds__(256) void prep_kernel(const float* __restrict__ X,
                                                   half_t* __restrict__ Xh,
                                                   half_t* __restrict__ U,
                                                   const float* __restrict__ c) {
  int lane = threadIdx.x & 63;
  int wid = blockIdx.x * 4 + (threadIdx.x >> 6);
  int nw = gridDim.x * 4;
  int sub = lane >> 4;
  for (int row = wid; row < NTOK; row += nw) {
#pragma unroll
    for (int ch = 0; ch < 4; ++ch) {
      int h = ch * 4 + sub;
      int idx = row * DIMF + ch * 256 + lane * 4;
      float4 x = *(const float4*)&X[idx];
      float s = x.x * x.x + x.y * x.y + x.z * x.z + x.w * x.w;
      s = wsum16(s);
      float k = c[h];
      float sk = sqrtf(fmaxf(fabsf(k), 1e-15f));
      float yn = fmaxf(sqrtf(s), 1e-15f);
      float t = fminf(yn * sk, 1.f - 1e-7f);
      float f = fatanh01(t) * frcp(sk) * frcp(yn);
      half4 xh4 = {(half_t)x.x, (half_t)x.y, (half_t)x.z, (half_t)x.w};
      *(half4*)&Xh[idx] = xh4;
      half4 u4 = {(half_t)(x.x * f), (half_t)(x.y * f), (half_t)(x.z * f), (half_t)(x.w * f)};
      *(half4*)&U[idx] = u4;
    }
  }
}

// ======= pass 2: ctxT[h][e][d] = sum_n v2h[n,h,d]*xh[n,h,e] ===============
#define TOK2 512
__global__ __launch_bounds__(256) void attn_pass2(const half_t* __restrict__ v2h,
                                                  const half_t* __restrict__ xh,
                                                  float* __restrict__ ctxT,
                                                  int sv2, int sx) {
  __shared__ float v2s[16][64];
  __shared__ float xs[16][64];
  int tid = threadIdx.x;
  int h = blockIdx.y;
  int n0 = blockIdx.x * TOK2;
  int e = tid & 63;
  int dg = tid >> 6;
  int ltt = tid >> 4;
  int lcol = (tid & 15) * 4;
  float acc[16];
#pragma unroll
  for (int i = 0; i < 16; ++i) acc[i] = 0.f;
  for (int t = 0; t < TOK2; t += 16) {
    __syncthreads();
    size_t gv = (size_t)(n0 + t + ltt) * sv2 + h * DHD + lcol;
    size_t gx = (size_t)(n0 + t + ltt) * sx + h * DHD + lcol;
    half4 a = *(const half4*)&v2h[gv];
    half4 b = *(const half4*)&xh[gx];
    *(float4*)&v2s[ltt][lcol] = make_float4((float)a.x, (float)a.y, (float)a.z, (float)a.w);
    *(float4*)&xs[ltt][lcol] = make_float4((float)b.x, (float)b.y, (float)b.z, (float)b.w);
    __syncthreads();
#pragma unroll
    for (int tt = 0; tt < 16; ++tt) {
      float xv = xs[tt][e];
      float4 p0 = *(const float4*)&v2s[tt][dg * 16 + 0];
      float4 p1 = *(const float4*)&v2s[tt][dg * 16 + 4];
      float4 p2 = *(const float4*)&v2s[tt][dg * 16 + 8];
      float4 p3 = *(const float4*)&v2s[tt][dg * 16 + 12];
      acc[0] = fmaf(p0.x, xv, acc[0]);   acc[1] = fmaf(p0.y, xv, acc[1]);
      acc[2] = fmaf(p0.z, xv, acc[2]);   acc[3] = fmaf(p0.w, xv, acc[3]);
      acc[4] = fmaf(p1.x, xv, acc[4]);   acc[5] = fmaf(p1.y, xv, acc[5]);
      acc[6] = fmaf(p1.z, xv, acc[6]);   acc[7] = fmaf(p1.w, xv, acc[7]);
      acc[8] = fmaf(p2.x, xv, acc[8]);   acc[9] = fmaf(p2.y, xv, acc[9]);
      acc[10] = fmaf(p2.z, xv, acc[10]); acc[11] = fmaf(p2.w, xv, acc[11]);
      acc[12] = fmaf(p3.x, xv, acc[12]); acc[13] = fmaf(p3.y, xv, acc[13]);
      acc[14] = fmaf(p3.z, xv, acc[14]); acc[15] = fmaf(p3.w, xv, acc[15]);
    }
  }
#pragma unroll
  for (int i = 0; i < 16; ++i)
    atomicAdd(&ctxT[h * 4096 + e * 64 + dg * 16 + i], acc[i]);
}

// ======= pass 3 (MFMA): Xo = Dinv * (v1h @ ctx), fused Dinv + mobius epi
__global__ __launch_bounds__(256) void attn_pass3m(const half_t* __restrict__ v1h,
                                                   const float* __restrict__ ctxT,
                                                   const float* __restrict__ v2sum,
                                                   const float* __restrict__ c_at,
                                                   const float* __restrict__ c_ff,
                                                   half_t* __restrict__ Uff,
                                                   int sv1) {
  __shared__ half_t sctx[8 * 64 * 8];
  int tid = threadIdx.x;
  int h = blockIdx.y;
  int m0 = blockIdx.x * 64;
  for (int ci = tid; ci < 512; ci += 256) {
    int t = ci >> 6, l = ci & 63;
    int j = t & 3, ks = t >> 2;
    int e2 = j * 16 + (l & 15);
    int d = ks * 32 + (l >> 4) * 8;
    const float* src = &ctxT[h * 4096 + e2 * 64 + d];
    half8 hh;
#pragma unroll
    for (int q = 0; q < 8; ++q) hh[q] = (half_t)src[q];
    *(half8*)&sctx[ci * 8] = hh;
  }
  __syncthreads();

  int lane = tid & 63;
  int w = tid >> 6;
  int quad = lane >> 4;
  int e = lane & 15;

  const half_t* ap = v1h + (size_t)(m0 + w * 16 + e) * sv1 + h * DHD + quad * 8;
  half8 a0 = *(const half8*)ap;
  half8 a1 = *(const half8*)(ap + 32);

  const float* vsp = v2sum + h * DHD + quad * 8;
  float4 va = *(const float4*)&vsp[0];
  float4 vb = *(const float4*)&vsp[4];
  float4 vc = *(const float4*)&vsp[32];
  float4 vd = *(const float4*)&vsp[36];
  float dn = (float)a0[0] * va.x + (float)a0[1] * va.y + (float)a0[2] * va.z + (float)a0[3] * va.w +
             (float)a0[4] * vb.x + (float)a0[5] * vb.y + (float)a0[6] * vb.z + (float)a0[7] * vb.w +
             (float)a1[0] * vc.x + (float)a1[1] * vc.y + (float)a1[2] * vc.z + (float)a1[3] * vc.w +
             (float)a1[4] * vd.x + (float)a1[5] * vd.y + (float)a1[6] * vd.z + (float)a1[7] * vd.w;
  dn += __shfl_xor(dn, 16, 64);
  dn += __shfl_xor(dn, 32, 64);
  float di = frcp((dn == 0.f) ? 1e-5f : dn);

  floatx4 acc[4];
#pragma unroll
  for (int j = 0; j < 4; ++j) acc[j] = (floatx4){0.f, 0.f, 0.f, 0.f};
#pragma unroll
  for (int j = 0; j < 4; ++j) {
    half8 b0 = *(const half8*)&sctx[((0 * 4 + j) * 64 + lane) * 8];
    half8 b1 = *(const half8*)&sctx[((1 * 4 + j) * 64 + lane) * 8];
    acc[j] = __builtin_amdgcn_mfma_f32_16x16x32_f16(a0, b0, acc[j], 0, 0, 0);
    acc[j] = __builtin_amdgcn_mfma_f32_16x16x32_f16(a1, b1, acc[j], 0, 0, 0);
  }

  float ka = c_at[h];
  float sk_a = sqrtf(fmaxf(fabsf(ka), 1e-15f));
  float rsk_a = frcp(sk_a);
  float maxn_a = (1.f - 1e-5f) * rsk_a;
  float kf = c_ff[h];
  float sk_f = sqrtf(fmaxf(fabsf(kf), 1e-15f));
  float rsk_f = frcp(sk_f);

#pragma unroll
  for (int r = 0; r < 4; ++r) {
    float Di = __shfl(di, quad * 4 + r, 64);
    float v0 = acc[0][r], v1 = acc[1][r], v2 = acc[2][r], v3 = acc[3][r];
    float s = v0 * v0 + v1 * v1 + v2 * v2 + v3 * v3;
    s = wsum16(s);
    int row = m0 + w * 16 + quad * 4 + r;
    float f = Di;
    float xn = fmaxf(sqrtf(s) * Di, 1e-15f);
    if (xn > maxn_a) { f *= maxn_a * frcp(xn); xn = maxn_a; }
    float t = fminf(xn * sk_a, 1.f - 1e-7f);
    float ar = fatanh01(t) * rsk_a;
    float tk = ftanh_pos(0.5f * ar * sk_a) * rsk_a;
    f *= tk * frcp(xn);
    float nn = tk;
    if (nn > maxn_a) { f *= maxn_a * frcp(nn); nn = maxn_a; }
    float fn = fmaxf(nn, 1e-15f);
    float t2 = fminf(fn * sk_f, 1.f - 1e-7f);
    float ar2 = fatanh01(t2) * rsk_f;
    f *= ar2 * frcp(fn);
    size_t base = (size_t)row * DIMF + h * DHD + e;
    Uff[base + 0] = (half_t)(v0 * f);
    Uff[base + 16] = (half_t)(v1 * f);
    Uff[base + 32] = (half_t)(v2 * f);
    Uff[base + 48] = (half_t)(v3 * f);
  }
}

extern "C" void kernel_launch(void* const* d_in, const int* in_sizes, int n_in,
                              void* d_out, int out_size, void* d_ws, size_t ws_size,
                              hipStream_t stream) {
  const float* X = (const float*)d_in[0];
  const float* mask = (const float*)d_in[1];
  const float* Wq = (const float*)d_in[2];
  const float* bq = (const float*)d_in[3];
  const float* Wk = (const float*)d_in[4];
  const float* bk = (const float*)d_in[5];
  const float* Wv = (const float*)d_in[6];
  const float* bv = (const float*)d_in[7];
  const float* c_v = (const float*)d_in[8];
  const float* c_at = (const float*)d_in[9];
  const float* Wff = (const float*)d_in[10];
  const float* bff = (const float*)d_in[11];
  const float* c_ff = (const float*)d_in[12];
  float* out = (float*)d_out;

  const size_t NE = (size_t)NTOK * DIMF;
  float* v2sum = (float*)d_ws;         // 1024
  float* ctxT = v2sum + 1024;          // 65536
  float* sbV = ctxT + 65536;           // 1024
  float* sbF = sbV + 1024;             // 1024
  float* y2V = sbF + 1024;             // 16
  float* y2F = y2V + 16;               // 16
  float* bqk = y2F + 16;               // 2048
  half_t* H1 = (half_t*)(bqk + 2048);  // Xh -> Uff
  half_t* H2 = H1 + NE;                // Uv (logmap input for V)
  half_t* HQK = H2 + NE;               // [16384][2048]: Q|K -> v1|v2
  half_t* H5 = HQK + 2 * NE;           // xh
  half_t* Wh0 = H5 + NE;               // 4 x 2MB f16 weights (Wq,Wk contiguous!)

  WPack pk;
  pk.w[0] = Wq; pk.w[1] = Wk; pk.w[2] = Wv; pk.w[3] = Wff;
  for (int i = 0; i < 4; ++i) pk.h[i] = Wh0 + (size_t)i * DIMF * DIMF;

  EpiArgs epN{};
  EpiArgs epV{sbV, y2V, c_v, c_at, mask, HQK, HQK + 1024, H5, v2sum, NQK};
  EpiArgs epF{sbF, y2F, c_ff, nullptr, nullptr, nullptr, nullptr, nullptr, nullptr, 0};

  convert_w_kernel<<<dim3(1024, 4), 256, 0, stream>>>(pk);
  prep_sb_kernel<<<1, 128, 0, stream>>>(bv, c_v, bff, c_ff, bq, bk, sbV, y2V, sbF, y2F, bqk);
  prep_kernel<<<512, 256, 0, stream>>>(X, H1, H2, c_v);
  hipMemsetAsync(v2sum, 0, (1024 + 65536) * sizeof(float), stream);
  // QK fused GEMM: [16384,2048] = Xh @ [Wq;Wk]^T + [bq;bk]
  gemm_f16<0, half_t><<<dim3(NQK / 128, NTOK / 128), 256, 0, stream>>>(
      H1, pk.h[0], bqk, HQK, NTOK, NQK, DIMF, epN);
  // V with fused stereo + attention pass 1 (transforms Q,K in place)
  gemm_f16<1, half_t><<<dim3(DIMF / 128, NTOK / 128), 256, 0, stream>>>(
      H2, pk.h[2], nullptr, (half_t*)nullptr, NTOK, DIMF, DIMF, epV);
  // attention core
  attn_pass2<<<dim3(NTOK / TOK2, NH), 256, 0, stream>>>(HQK + 1024, H5, ctxT, NQK, DIMF);
  attn_pass3m<<<dim3(NTOK / 64, NH), 256, 0, stream>>>(HQK, ctxT, v2sum, c_at, c_ff, H1, NQK);
  // FF with fused stereo -> final fp32 out
  gemm_f16<2, float><<<dim3(DIMF / 128, NTOK / 128), 256, 0, stream>>>(
      H1, pk.h[3], nullptr, out, NTOK, DIMF, DIMF, epF);
}

// Round 5
// 636.366 us; speedup vs baseline: 4.4628x; 1.0266x over previous
//
#include <hip/hip_runtime.h>
#include <math.h>
#include <stdint.h>

#define NTOK 16384
#define DIMF 1024
#define NH 16
#define DHD 64
#define NQK 2048

typedef _Float16 half_t;
typedef __attribute__((ext_vector_type(8))) _Float16 half8;
typedef __attribute__((ext_vector_type(4))) _Float16 half4;
typedef __attribute__((ext_vector_type(4))) float floatx4;

__device__ __forceinline__ float wsum(float v) {
  v += __shfl_xor(v, 32, 64);
  v += __shfl_xor(v, 16, 64);
  v += __shfl_xor(v, 8, 64);
  v += __shfl_xor(v, 4, 64);
  v += __shfl_xor(v, 2, 64);
  v += __shfl_xor(v, 1, 64);
  return v;
}
__device__ __forceinline__ float wsum16(float v) {
  v += __shfl_xor(v, 1, 64);
  v += __shfl_xor(v, 2, 64);
  v += __shfl_xor(v, 4, 64);
  v += __shfl_xor(v, 8, 64);
  return v;
}

__device__ __forceinline__ float frcp(float x) { return __builtin_amdgcn_rcpf(x); }
__device__ __forceinline__ float fexp(float x) { return __expf(x); }
__device__ __forceinline__ float flog(float x) { return __logf(x); }
__device__ __forceinline__ float ftanh_pos(float x) {  // tanh, x >= 0
  float e = fexp(2.f * x);
  return 1.f - 2.f * frcp(e + 1.f);
}
__device__ __forceinline__ float fatanh01(float t) {  // atanh, t in [0,1)
  return 0.5f * flog((1.f + t) * frcp(1.f - t));
}

__device__ __forceinline__ void gload16(const void* g, void* lds) {
  __builtin_amdgcn_global_load_lds(
      (const __attribute__((address_space(1))) uint32_t*)(uintptr_t)g,
      (__attribute__((address_space(3))) uint32_t*)(uintptr_t)lds, 16, 0, 0);
}

struct EpiArgs {
  const float* sb;     // [16][64] projected mobius bias per head
  const float* y2;     // [16] sbn^2 per head
  const float* c_st;   // stereo curvature (c_v or c_ff)
  const float* c_at;   // attention curvature (V mode)
  const float* mask;   // [NTOK] (V mode)
  half_t* Qh;          // V mode: in-place Q -> v1 (stride qstride)
  half_t* Kh;          // V mode: raw K input (stride qstride)
  half_t* v2T;         // V mode: out v2 transposed [h*64+d][NTOK]
  half_t* xT;          // V mode: out x  transposed [h*64+e][NTOK]
  float* v2sum;        // V mode: [16][64] atomics
  int qstride;         // row stride of Qh/Kh
};

// =============== GEMM: C[M,N] = A[M,K](f16) * B[N,K]^T(f16) ===============
// 128x128 tile, BK=64, 256 thr, per-wave 4x4 grid of 16x16x32 f16 MFMAs.
// LDS fragment-canonical: 1KB blocks of 64 chunks x 16B, chunk idx == lane.
// Each wave's epilogue region = 64 rows x 64 cols = one full head.
// MODE 0: plain f16 out + bias. MODE 1: fused stereo + attn-pass1 (V),
// writing v2/x TRANSPOSED for the MFMA ctx kernel. MODE 2: fused stereo ->
// fp32 out (FF, final output).
template <int MODE, typename OutT>
__global__ __launch_bounds__(256, 4) void gemm_f16(const half_t* __restrict__ A,
                                                   const half_t* __restrict__ B,
                                                   const float* __restrict__ bias,
                                                   OutT* __restrict__ C,
                                                   int M, int Nn, int K, EpiArgs ep) {
  __shared__ half_t sA[128 * 64];
  __shared__ half_t sB[128 * 64];
  const int tid = threadIdx.x;
  const int lane = tid & 63;
  const int w = tid >> 6;
  const int n0 = blockIdx.x * 128;
  const int m0 = blockIdx.y * 128;

  const half_t* srcA[4];
  const half_t* srcB[4];
  int dstOff[4];
#pragma unroll
  for (int t = 0; t < 4; ++t) {
    int idx = w * 4 + t;
    int ks = idx >> 3, g = idx & 7;
    int row = g * 16 + (lane & 15);
    int kof = ks * 32 + (lane >> 4) * 8;
    srcA[t] = A + (size_t)(m0 + row) * K + kof;
    srcB[t] = B + (size_t)(n0 + row) * K + kof;
    dstOff[t] = (ks * 8 + g) * 512;
  }

  floatx4 acc[4][4];
#pragma unroll
  for (int i = 0; i < 4; ++i)
#pragma unroll
    for (int j = 0; j < 4; ++j) acc[i][j] = (floatx4){0.f, 0.f, 0.f, 0.f};

  const int wr = (w >> 1) * 4;
  const int wc = (w & 1) * 4;

  for (int k0 = 0; k0 < K; k0 += 64) {
#pragma unroll
    for (int t = 0; t < 4; ++t) {
      gload16(srcA[t], sA + dstOff[t]);
      gload16(srcB[t], sB + dstOff[t]);
      srcA[t] += 64;
      srcB[t] += 64;
    }
    __syncthreads();
#pragma unroll
    for (int ks = 0; ks < 2; ++ks) {
      half8 af[4], bf[4];
#pragma unroll
      for (int i = 0; i < 4; ++i)
        af[i] = *(const half8*)&sA[(ks * 8 + wr + i) * 512 + lane * 8];
#pragma unroll
      for (int j = 0; j < 4; ++j)
        bf[j] = *(const half8*)&sB[(ks * 8 + wc + j) * 512 + lane * 8];
#pragma unroll
      for (int i = 0; i < 4; ++i)
#pragma unroll
        for (int j = 0; j < 4; ++j)
          acc[i][j] = __builtin_amdgcn_mfma_f32_16x16x32_f16(af[i], bf[j], acc[i][j], 0, 0, 0);
    }
    __syncthreads();
  }

  const int e = lane & 15;
  const int quad = lane >> 4;

  if constexpr (MODE == 0) {
#pragma unroll
    for (int j = 0; j < 4; ++j) {
      int col = n0 + (w & 1) * 64 + j * 16 + e;
      float bv = bias ? bias[col] : 0.f;
#pragma unroll
      for (int i = 0; i < 4; ++i) {
        int row = m0 + (w >> 1) * 64 + i * 16 + quad * 4;
#pragma unroll
        for (int r = 0; r < 4; ++r)
          C[(size_t)(row + r) * Nn + col] = (OutT)(acc[i][j][r] + bv);
      }
    }
  } else {
    const int hb = n0 + (w & 1) * 64;  // head base col
    const int h = hb >> 6;
    const float kst = ep.c_st[h];
    const float sk = sqrtf(fmaxf(fabsf(kst), 1e-15f));
    const float rsk = frcp(sk);
    const float maxn = (1.f - 1e-5f) * rsk;
    const float mx2 = maxn * maxn;
    float sbj[4];
#pragma unroll
    for (int j = 0; j < 4; ++j) sbj[j] = ep.sb[hb + j * 16 + e];
    const float y2h = ep.y2[h];
    float ka = 0.f, v2acc[4] = {0.f, 0.f, 0.f, 0.f};
    if constexpr (MODE == 1) ka = ep.c_at[h];
    const int rowbase = m0 + (w >> 1) * 64;

#pragma unroll
    for (int i = 0; i < 4; ++i) {
#pragma unroll
      for (int r = 0; r < 4; ++r) {
        const int row = rowbase + i * 16 + quad * 4 + r;
        float s = 0.f, dp = 0.f;
#pragma unroll
        for (int j = 0; j < 4; ++j) {
          float mv = acc[i][j][r];
          s += mv * mv;
          dp += mv * sbj[j];
        }
        s = wsum16(s);
        dp = wsum16(dp);
        // expmap0 + project
        float un = fmaxf(sqrtf(s), 1e-15f);
        float tn = ftanh_pos(un * sk) * rsk;
        float f = tn * frcp(un);
        float rn = fmaxf(tn, 1e-15f);
        if (rn > maxn) { f *= maxn * frcp(rn); rn = maxn; }
        // mobius_add(v, sb) + project
        float xy = dp * f;
        float x2 = rn * rn;
        float num1 = 1.f - 2.f * kst * xy - kst * y2h;
        float num2 = 1.f + kst * x2;
        float den = fmaxf(1.f - 2.f * kst * xy + kst * kst * x2 * y2h, 1e-15f);
        float rden = frcp(den);
        float c1 = num1 * f * rden;
        float c2 = num2 * rden;
        float o[4];
        float os = 0.f;
#pragma unroll
        for (int j = 0; j < 4; ++j) {
          o[j] = c1 * acc[i][j][r] + c2 * sbj[j];
          os += o[j] * o[j];
        }
        os = wsum16(os);
        float on = fmaxf(sqrtf(os), 1e-15f);
        if (on > maxn) {
          float sc = maxn * frcp(on);
#pragma unroll
          for (int j = 0; j < 4; ++j) o[j] *= sc;
        }
        if constexpr (MODE == 2) {
#pragma unroll
          for (int j = 0; j < 4; ++j)
            C[(size_t)row * Nn + hb + j * 16 + e] = (OutT)o[j];
        } else {
          // fused attn pass 1: v1 in-place; v2,x written TRANSPOSED
          float vn2 = fminf(os, mx2);
          float pt = fmaxf(1.f + ka * vn2, 1e-15f);
          float rpt = frcp(pt);
          float gamma = fmaxf(2.f * rpt, 1e-15f);
          float gm1 = gamma - 1.f;
          float aden = fmaxf(fabsf(gm1), 1e-10f);
          float den2 = (gm1 >= 0.f) ? aden : -aden;
          float mrow = ep.mask[row];
          float xsc = gamma * frcp(den2) * mrow;
          size_t qb = (size_t)row * ep.qstride + hb + e;
#pragma unroll
          for (int j = 0; j < 4; ++j) {
            size_t gi = qb + j * 16;
            float q = (float)ep.Qh[gi] * rpt;
            float v1 = (q > 0.f) ? (q + 1.f) : fexp(q);
            ep.Qh[gi] = (half_t)v1;
            float kv = (float)ep.Kh[gi] * rpt;
            float v2 = den2 * ((kv > 0.f) ? (kv + 1.f) : fexp(kv)) * mrow;
            size_t tb = (size_t)(hb + j * 16 + e) * NTOK + row;
            ep.v2T[tb] = (half_t)v2;
            v2acc[j] += v2;
            ep.xT[tb] = (half_t)(xsc * o[j]);
          }
        }
      }
    }
    if constexpr (MODE == 1) {
#pragma unroll
      for (int j = 0; j < 4; ++j) {
        float t = v2acc[j];
        t += __shfl_xor(t, 16, 64);
        t += __shfl_xor(t, 32, 64);
        if (quad == 0) atomicAdd(&ep.v2sum[h * DHD + j * 16 + e], t);
      }
    }
  }
}

// =============== weight convert fp32 -> f16 ===============================
struct WPack {
  const float* w[4];
  half_t* h[4];
};
__global__ __launch_bounds__(256) void convert_w_kernel(WPack pk) {
  int wi = blockIdx.y;
  const float* w = pk.w[wi];
  half_t* ph = pk.h[wi];
  int i = (blockIdx.x * 256 + threadIdx.x) * 4;
  float4 v = *(const float4*)&w[i];
  half4 hh = {(half_t)v.x, (half_t)v.y, (half_t)v.z, (half_t)v.w};
  *(half4*)&ph[i] = hh;
}

// ====== precompute projected mobius bias sb per head + combined QK bias ===
__global__ __launch_bounds__(128) void prep_sb_kernel(const float* __restrict__ bv,
                                                      const float* __restrict__ cv,
                                                      const float* __restrict__ bf,
                                                      const float* __restrict__ cf,
                                                      const float* __restrict__ bq,
                                                      const float* __restrict__ bk,
                                                      float* __restrict__ sbV,
                                                      float* __restrict__ y2V,
                                                      float* __restrict__ sbF,
                                                      float* __restrict__ y2F,
                                                      float* __restrict__ bqk) {
  int tid = threadIdx.x;
  for (int i = tid; i < 1024; i += 128) {
    bqk[i] = bq[i];
    bqk[1024 + i] = bk[i];
  }
  int wv = tid >> 6;
  int lane = tid & 63;
  const float* b = wv ? bf : bv;
  const float* c = wv ? cf : cv;
  float* sb = wv ? sbF : sbV;
  float* y2 = wv ? y2F : y2V;
  for (int h = 0; h < NH; ++h) {
    float k = c[h];
    float sk = sqrtf(fmaxf(fabsf(k), 1e-15f));
    float rsk = frcp(sk);
    float maxn = (1.f - 1e-5f) * rsk;
    float bb = b[h * DHD + lane];
    float bs = wsum(bb * bb);
    float bn = fmaxf(sqrtf(bs), 1e-15f);
    float tb = ftanh_pos(bn * sk) * rsk;
    float sv = tb * frcp(bn) * bb;
    float sbn = fmaxf(tb, 1e-15f);
    if (sbn > maxn) { sv *= maxn * frcp(sbn); sbn = maxn; }
    sb[h * DHD + lane] = sv;
    if (lane == 0) y2[h] = sbn * sbn;
  }
}

// =============== prep: Xh = f16(X); U = f16(logmap0(X, c_v)) ==============
__global__ __launch_bounds__(256) void prep_kernel(const float* __restrict__ X,
                                                   half_t* __restrict__ Xh,
                                                   half_t* __restrict__ U,
                                                   const float* __restrict__ c) {
  int lane = threadIdx.x & 63;
  int wid = blockIdx.x * 4 + (threadIdx.x >> 6);
  int nw = gridDim.x * 4;
  int sub = lane >> 4;
  for (int row = wid; row < NTOK; row += nw) {
#pragma unroll
    for (int ch = 0; ch < 4; ++ch) {
      int h = ch * 4 + sub;
      int idx = row * DIMF + ch * 256 + lane * 4;
      float4 x = *(const float4*)&X[idx];
      float s = x.x * x.x + x.y * x.y + x.z * x.z + x.w * x.w;
      s = wsum16(s);
      float k = c[h];
      float sk = sqrtf(fmaxf(fabsf(k), 1e-15f));
      float yn = fmaxf(sqrtf(s), 1e-15f);
      float t = fminf(yn * sk, 1.f - 1e-7f);
      float f = fatanh01(t) * frcp(sk) * frcp(yn);
      half4 xh4 = {(half_t)x.x, (half_t)x.y, (half_t)x.z, (half_t)x.w};
      *(half4*)&Xh[idx] = xh4;
      half4 u4 = {(half_t)(x.x * f), (half_t)(x.y * f), (half_t)(x.z * f), (half_t)(x.w * f)};
      *(half4*)&U[idx] = u4;
    }
  }
}

// ======= pass 2 (MFMA, streaming): ctxT[h][e][d] += xT[e,:]·v2T[d,:] ======
// Operands are pre-transposed [h*64+dim][NTOK] so both MFMA fragments are
// contiguous half8 global loads. Per wave: 4 chunks of 32 tokens, 8 loads +
// 16 MFMAs each; no barriers in the hot loop. Cross-wave reduce via LDS
// atomics, then one global-atomic flush per block.
__global__ __launch_bounds__(256) void attn_pass2(const half_t* __restrict__ v2T,
                                                  const half_t* __restrict__ xT,
                                                  float* __restrict__ ctxT) {
  __shared__ float red[4096];
  int tid = threadIdx.x;
  int h = blockIdx.y;
  for (int i = tid; i < 4096; i += 256) red[i] = 0.f;
  __syncthreads();
  int lane = tid & 63;
  int w = tid >> 6;
  int m = lane & 15;
  int q = lane >> 4;
  const half_t* xb = xT + (size_t)h * 64 * NTOK;
  const half_t* vb = v2T + (size_t)h * 64 * NTOK;
  floatx4 acc[4][4];
#pragma unroll
  for (int i = 0; i < 4; ++i)
#pragma unroll
    for (int j = 0; j < 4; ++j) acc[i][j] = (floatx4){0.f, 0.f, 0.f, 0.f};

  int tok0 = blockIdx.x * 512 + w * 32 + q * 8;
#pragma unroll
  for (int c = 0; c < 4; ++c) {
    int tk = tok0 + c * 128;
    half8 af[4], bf[4];
#pragma unroll
    for (int i = 0; i < 4; ++i)
      af[i] = *(const half8*)&xb[(size_t)(i * 16 + m) * NTOK + tk];
#pragma unroll
    for (int j = 0; j < 4; ++j)
      bf[j] = *(const half8*)&vb[(size_t)(j * 16 + m) * NTOK + tk];
#pragma unroll
    for (int i = 0; i < 4; ++i)
#pragma unroll
      for (int j = 0; j < 4; ++j)
        acc[i][j] = __builtin_amdgcn_mfma_f32_16x16x32_f16(af[i], bf[j], acc[i][j], 0, 0, 0);
  }
  // reduce 4 waves through LDS atomics
#pragma unroll
  for (int i = 0; i < 4; ++i)
#pragma unroll
    for (int j = 0; j < 4; ++j)
#pragma unroll
      for (int r = 0; r < 4; ++r) {
        int e = i * 16 + q * 4 + r;
        int d = j * 16 + m;
        atomicAdd(&red[e * 64 + d], acc[i][j][r]);
      }
  __syncthreads();
  float* dst = ctxT + (size_t)h * 4096;
  for (int i = tid; i < 4096; i += 256) atomicAdd(&dst[i], red[i]);
}

// ======= pass 3 (MFMA): Xo = Dinv * (v1h @ ctx), fused Dinv + mobius epi
__global__ __launch_bounds__(256) void attn_pass3m(const half_t* __restrict__ v1h,
                                                   const float* __restrict__ ctxT,
                                                   const float* __restrict__ v2sum,
                                                   const float* __restrict__ c_at,
                                                   const float* __restrict__ c_ff,
                                                   half_t* __restrict__ Uff,
                                                   int sv1) {
  __shared__ half_t sctx[8 * 64 * 8];
  int tid = threadIdx.x;
  int h = blockIdx.y;
  int m0 = blockIdx.x * 64;
  for (int ci = tid; ci < 512; ci += 256) {
    int t = ci >> 6, l = ci & 63;
    int j = t & 3, ks = t >> 2;
    int e2 = j * 16 + (l & 15);
    int d = ks * 32 + (l >> 4) * 8;
    const float* src = &ctxT[h * 4096 + e2 * 64 + d];
    half8 hh;
#pragma unroll
    for (int q = 0; q < 8; ++q) hh[q] = (half_t)src[q];
    *(half8*)&sctx[ci * 8] = hh;
  }
  __syncthreads();

  int lane = tid & 63;
  int w = tid >> 6;
  int quad = lane >> 4;
  int e = lane & 15;

  const half_t* ap = v1h + (size_t)(m0 + w * 16 + e) * sv1 + h * DHD + quad * 8;
  half8 a0 = *(const half8*)ap;
  half8 a1 = *(const half8*)(ap + 32);

  const float* vsp = v2sum + h * DHD + quad * 8;
  float4 va = *(const float4*)&vsp[0];
  float4 vb = *(const float4*)&vsp[4];
  float4 vc = *(const float4*)&vsp[32];
  float4 vd = *(const float4*)&vsp[36];
  float dn = (float)a0[0] * va.x + (float)a0[1] * va.y + (float)a0[2] * va.z + (float)a0[3] * va.w +
             (float)a0[4] * vb.x + (float)a0[5] * vb.y + (float)a0[6] * vb.z + (float)a0[7] * vb.w +
             (float)a1[0] * vc.x + (float)a1[1] * vc.y + (float)a1[2] * vc.z + (float)a1[3] * vc.w +
             (float)a1[4] * vd.x + (float)a1[5] * vd.y + (float)a1[6] * vd.z + (float)a1[7] * vd.w;
  dn += __shfl_xor(dn, 16, 64);
  dn += __shfl_xor(dn, 32, 64);
  float di = frcp((dn == 0.f) ? 1e-5f : dn);

  floatx4 acc[4];
#pragma unroll
  for (int j = 0; j < 4; ++j) acc[j] = (floatx4){0.f, 0.f, 0.f, 0.f};
#pragma unroll
  for (int j = 0; j < 4; ++j) {
    half8 b0 = *(const half8*)&sctx[((0 * 4 + j) * 64 + lane) * 8];
    half8 b1 = *(const half8*)&sctx[((1 * 4 + j) * 64 + lane) * 8];
    acc[j] = __builtin_amdgcn_mfma_f32_16x16x32_f16(a0, b0, acc[j], 0, 0, 0);
    acc[j] = __builtin_amdgcn_mfma_f32_16x16x32_f16(a1, b1, acc[j], 0, 0, 0);
  }

  float ka = c_at[h];
  float sk_a = sqrtf(fmaxf(fabsf(ka), 1e-15f));
  float rsk_a = frcp(sk_a);
  float maxn_a = (1.f - 1e-5f) * rsk_a;
  float kf = c_ff[h];
  float sk_f = sqrtf(fmaxf(fabsf(kf), 1e-15f));
  float rsk_f = frcp(sk_f);

#pragma unroll
  for (int r = 0; r < 4; ++r) {
    float Di = __shfl(di, quad * 4 + r, 64);
    float v0 = acc[0][r], v1 = acc[1][r], v2 = acc[2][r], v3 = acc[3][r];
    float s = v0 * v0 + v1 * v1 + v2 * v2 + v3 * v3;
    s = wsum16(s);
    int row = m0 + w * 16 + quad * 4 + r;
    float f = Di;
    float xn = fmaxf(sqrtf(s) * Di, 1e-15f);
    if (xn > maxn_a) { f *= maxn_a * frcp(xn); xn = maxn_a; }
    float t = fminf(xn * sk_a, 1.f - 1e-7f);
    float ar = fatanh01(t) * rsk_a;
    float tk = ftanh_pos(0.5f * ar * sk_a) * rsk_a;
    f *= tk * frcp(xn);
    float nn = tk;
    if (nn > maxn_a) { f *= maxn_a * frcp(nn); nn = maxn_a; }
    float fn = fmaxf(nn, 1e-15f);
    float t2 = fminf(fn * sk_f, 1.f - 1e-7f);
    float ar2 = fatanh01(t2) * rsk_f;
    f *= ar2 * frcp(fn);
    size_t base = (size_t)row * DIMF + h * DHD + e;
    Uff[base + 0] = (half_t)(v0 * f);
    Uff[base + 16] = (half_t)(v1 * f);
    Uff[base + 32] = (half_t)(v2 * f);
    Uff[base + 48] = (half_t)(v3 * f);
  }
}

extern "C" void kernel_launch(void* const* d_in, const int* in_sizes, int n_in,
                              void* d_out, int out_size, void* d_ws, size_t ws_size,
                              hipStream_t stream) {
  const float* X = (const float*)d_in[0];
  const float* mask = (const float*)d_in[1];
  const float* Wq = (const float*)d_in[2];
  const float* bq = (const float*)d_in[3];
  const float* Wk = (const float*)d_in[4];
  const float* bk = (const float*)d_in[5];
  const float* Wv = (const float*)d_in[6];
  const float* bv = (const float*)d_in[7];
  const float* c_v = (const float*)d_in[8];
  const float* c_at = (const float*)d_in[9];
  const float* Wff = (const float*)d_in[10];
  const float* bff = (const float*)d_in[11];
  const float* c_ff = (const float*)d_in[12];
  float* out = (float*)d_out;

  const size_t NE = (size_t)NTOK * DIMF;
  float* v2sum = (float*)d_ws;         // 1024
  float* ctxT = v2sum + 1024;          // 65536
  float* sbV = ctxT + 65536;           // 1024
  float* sbF = sbV + 1024;             // 1024
  float* y2V = sbF + 1024;             // 16
  float* y2F = y2V + 16;               // 16
  float* bqk = y2F + 16;               // 2048
  half_t* H1 = (half_t*)(bqk + 2048);  // Xh -> Uff
  half_t* H2 = H1 + NE;                // Uv (logmap input for V)
  half_t* HQK = H2 + NE;               // [16384][2048]: Q|K -> v1|K
  half_t* V2T = HQK + 2 * NE;          // [16*64][16384] v2 transposed
  half_t* XT = V2T + NE;               // [16*64][16384] x transposed
  half_t* Wh0 = XT + NE;               // 4 x 2MB f16 weights (Wq,Wk contiguous!)

  WPack pk;
  pk.w[0] = Wq; pk.w[1] = Wk; pk.w[2] = Wv; pk.w[3] = Wff;
  for (int i = 0; i < 4; ++i) pk.h[i] = Wh0 + (size_t)i * DIMF * DIMF;

  EpiArgs epN{};
  EpiArgs epV{sbV, y2V, c_v, c_at, mask, HQK, HQK + 1024, V2T, XT, v2sum, NQK};
  EpiArgs epF{sbF, y2F, c_ff, nullptr, nullptr, nullptr, nullptr, nullptr, nullptr, nullptr, 0};

  convert_w_kernel<<<dim3(1024, 4), 256, 0, stream>>>(pk);
  prep_sb_kernel<<<1, 128, 0, stream>>>(bv, c_v, bff, c_ff, bq, bk, sbV, y2V, sbF, y2F, bqk);
  prep_kernel<<<512, 256, 0, stream>>>(X, H1, H2, c_v);
  hipMemsetAsync(v2sum, 0, (1024 + 65536) * sizeof(float), stream);
  // QK fused GEMM: [16384,2048] = Xh @ [Wq;Wk]^T + [bq;bk]
  gemm_f16<0, half_t><<<dim3(NQK / 128, NTOK / 128), 256, 0, stream>>>(
      H1, pk.h[0], bqk, HQK, NTOK, NQK, DIMF, epN);
  // V with fused stereo + attention pass 1 (v1 in place; v2/x transposed out)
  gemm_f16<1, half_t><<<dim3(DIMF / 128, NTOK / 128), 256, 0, stream>>>(
      H2, pk.h[2], nullptr, (half_t*)nullptr, NTOK, DIMF, DIMF, epV);
  // attention core
  attn_pass2<<<dim3(NTOK / 512, NH), 256, 0, stream>>>(V2T, XT, ctxT);
  attn_pass3m<<<dim3(NTOK / 64, NH), 256, 0, stream>>>(HQK, ctxT, v2sum, c_at, c_ff, H1, NQK);
  // FF with fused stereo -> final fp32 out
  gemm_f16<2, float><<<dim3(DIMF / 128, NTOK / 128), 256, 0, stream>>>(
      H1, pk.h[3], nullptr, out, NTOK, DIMF, DIMF, epF);
}